// Round 4
// baseline (2059.054 us; speedup 1.0000x reference)
//
#include <hip/hip_runtime.h>
#include <hip/hip_bf16.h>

#define N_ 100000
#define E_ 300000
#define ETOT 400000
#define G_ 2048
#define NB_SCAN 98        // ceil(N_/1024)
#define NB_SCAN2 391      // ceil(ETOT/1024)

typedef __attribute__((ext_vector_type(8))) short bf16x8;
typedef __attribute__((ext_vector_type(4))) float f32x4;

__device__ __forceinline__ short f2bf(float f) {
    __hip_bfloat16 h = __float2bfloat16(f);
    return *reinterpret_cast<short*>(&h);
}
__device__ __forceinline__ float bf2f(short s) {
    __hip_bfloat16 h = *reinterpret_cast<__hip_bfloat16*>(&s);
    return __bfloat162float(h);
}

// async global->LDS, 16B per lane. LDS dest is wave-uniform base + lane*16.
typedef __attribute__((address_space(1))) void* gas_ptr;
typedef __attribute__((address_space(3))) void* las_ptr;
__device__ __forceinline__ void gload16(const void* g, void* l) {
    __builtin_amdgcn_global_load_lds((gas_ptr)g, (las_ptr)l, 16, 0, 0);
}

// bijective XCD swizzle (m204): physical bid b=xcd+8i -> contiguous virtual chunk per XCD
__device__ __forceinline__ int xcd_swz(int bid, int nwg) {
    int q = nwg >> 3, rr = nwg & 7;
    int xcd = bid & 7, i = bid >> 3;
    return (xcd < rr) ? xcd * (q + 1) + i : rr * (q + 1) + (xcd - rr) * q + i;
}

// ---------------- mean of edge_attr over rows -> meansum[64] (sum; divide later)
__global__ __launch_bounds__(256) void mean_kernel(const float* __restrict__ ea, float* __restrict__ meansum) {
    __shared__ float s[256];
    int tid = threadIdx.x;
    int col = tid & 63, rg = tid >> 6;
    float acc = 0.f;
    for (long long row = (long long)blockIdx.x * 4 + rg; row < E_; row += (long long)gridDim.x * 4)
        acc += ea[row * 64 + col];
    s[tid] = acc;
    __syncthreads();
    if (tid < 64) atomicAdd(meansum + tid, s[tid] + s[tid + 64] + s[tid + 128] + s[tid + 192]);
}

// ---------------- loop_e[c] = (meansum/E) @ We_l
__global__ __launch_bounds__(256) void loope_kernel(const float* __restrict__ meansum,
                                                    const float* __restrict__ We_l,
                                                    float* __restrict__ loope) {
    int c = threadIdx.x;
    float acc = 0.f;
    const float invE = 1.0f / (float)E_;
    for (int k = 0; k < 64; k++) acc += (meansum[k] * invE) * We_l[k * 256 + c];
    loope[c] = acc;
}

// swizzled column within 32-col window: chunk c -> c ^ ((row>>1)&3)
__device__ __forceinline__ int swz_col(int row, int k) {
    int c = (k >> 3) & 3;
    int s = (row >> 1) & 3;
    return (k & ~31) | ((c ^ s) << 3) | (k & 7);
}

// ---------------- weight prep: split fp32 -> (hi,lo) bf16, transposed to [n][k], pre-swizzled
__global__ __launch_bounds__(256) void prep_wcat_kernel(const float* __restrict__ Wl, const float* __restrict__ Wr,
                                                        short* __restrict__ hi, short* __restrict__ lo) {
    int idx = blockIdx.x * 256 + threadIdx.x;
    if (idx >= 3 * 512 * 256) return;
    int l = idx / (512 * 256);
    int rem = idx % (512 * 256);
    int n = rem >> 8, k = rem & 255;
    float v = (n < 256) ? Wl[((size_t)l * 256 + k) * 256 + n]
                        : Wr[((size_t)l * 256 + k) * 256 + (n - 256)];
    short h = f2bf(v);
    size_t o = (size_t)l * 512 * 256 + (size_t)n * 256 + swz_col(n, k);
    hi[o] = h;
    lo[o] = f2bf(v - bf2f(h));
}

__global__ __launch_bounds__(256) void prep_we_kernel(const float* __restrict__ We,
                                                      short* __restrict__ hi) {
    int idx = blockIdx.x * 256 + threadIdx.x;
    if (idx >= 3 * 256 * 64) return;
    int l = idx / (256 * 64);
    int rem = idx % (256 * 64);
    int n = rem >> 6, k = rem & 63;
    float v = We[((size_t)l * 64 + k) * 256 + n];
    hi[(size_t)l * 256 * 64 + (size_t)n * 64 + swz_col(n, k)] = f2bf(v);
}

// ---------------- split x fp32 [N_][256] -> pre-swizzled bf16 hi/lo
__global__ __launch_bounds__(256) void split_x_kernel(const float* __restrict__ in,
                                                      short* __restrict__ hi, short* __restrict__ lo) {
    int idx = blockIdx.x * 256 + threadIdx.x;
    if (idx >= N_ * 32) return;
    int gm = idx >> 5, cw = idx & 31;
    int c = cw & 3, win = cw >> 2;
    int s = (gm >> 1) & 3;
    const float* src = in + (size_t)gm * 256 + (win << 5) + (c << 3);
    float4 f0 = *(const float4*)src;
    float4 f1 = *(const float4*)(src + 4);
    float f[8] = {f0.x, f0.y, f0.z, f0.w, f1.x, f1.y, f1.z, f1.w};
    bf16x8 vh, vl;
#pragma unroll
    for (int j = 0; j < 8; j++) {
        short h = f2bf(f[j]);
        vh[j] = h;
        vl[j] = f2bf(f[j] - bf2f(h));
    }
    size_t o = (size_t)gm * 256 + (win << 5) + ((c ^ s) << 3);
    *(bf16x8*)(hi + o) = vh;
    *(bf16x8*)(lo + o) = vl;
}

// ---------------- eattr fp32 [E_][64] -> bf16, permuted to RANK (compacted CSR) order, pre-swizzled
__global__ __launch_bounds__(256) void split_e_kernel(const float* __restrict__ in, short* __restrict__ hi,
                                                      const int* __restrict__ pose, const int* __restrict__ rnk) {
    int idx = blockIdx.x * 256 + threadIdx.x;
    if (idx >= E_ * 8) return;
    int e = idx >> 3, cw = idx & 7;
    int c = cw & 3, win = cw >> 2;
    int rk = rnk[pose[e]];
    int s = (rk >> 1) & 3;
    const float* src = in + (size_t)e * 64 + (win << 5) + (c << 3);
    float4 f0 = *(const float4*)src;
    float4 f1 = *(const float4*)(src + 4);
    float f[8] = {f0.x, f0.y, f0.z, f0.w, f1.x, f1.y, f1.z, f1.w};
    bf16x8 vh;
#pragma unroll
    for (int j = 0; j < 8; j++) vh[j] = f2bf(f[j]);
    *(bf16x8*)(hi + (size_t)rk * 64 + (win << 5) + ((c ^ s) << 3)) = vh;
}

// ---------------- CSR build over dst (self loops e>=E_ have dst = e-E_)
__global__ __launch_bounds__(256) void hist_kernel(const int* __restrict__ ei, int* __restrict__ deg) {
    int e = blockIdx.x * 256 + threadIdx.x;
    if (e >= ETOT) return;
    int d = (e < E_) ? ei[E_ + e] : (e - E_);
    atomicAdd(deg + d, 1);
}

__global__ __launch_bounds__(256) void scanA_kernel(const int* __restrict__ deg, int* __restrict__ off,
                                                    int* __restrict__ bsum) {
    __shared__ int s[256];
    int tid = threadIdx.x;
    int base = blockIdx.x * 1024 + tid * 4;
    int v[4];
#pragma unroll
    for (int i = 0; i < 4; i++) v[i] = (base + i < N_) ? deg[base + i] : 0;
    v[1] += v[0]; v[2] += v[1]; v[3] += v[2];
    s[tid] = v[3];
    __syncthreads();
    for (int o = 1; o < 256; o <<= 1) {
        int t = (tid >= o) ? s[tid - o] : 0;
        __syncthreads();
        s[tid] += t;
        __syncthreads();
    }
    int prev = tid ? s[tid - 1] : 0;
#pragma unroll
    for (int i = 0; i < 4; i++)
        if (base + i < N_) off[base + i + 1] = prev + v[i];
    if (tid == 255) bsum[blockIdx.x] = s[255];
}

__global__ void scanB_kernel(int* __restrict__ bsum, int n) {
    if (threadIdx.x == 0) {
        int run = 0;
        for (int i = 0; i < n; i++) { int t = bsum[i]; bsum[i] = run; run += t; }
    }
}

__global__ __launch_bounds__(256) void scanC_kernel(int* __restrict__ off, const int* __restrict__ bsum) {
    int i = blockIdx.x * 256 + threadIdx.x;
    if (i < N_) {
        off[i + 1] += bsum[i >> 10];
        if (i == 0) off[0] = 0;
    }
}

// scatter: srcs[pos]=src; dstp[pos]=dst; pose[e]=pos
__global__ __launch_bounds__(256) void scatter_kernel(const int* __restrict__ ei, int* __restrict__ cursor,
                                                      int* __restrict__ srcs, int* __restrict__ dstp,
                                                      int* __restrict__ pose) {
    int e = blockIdx.x * 256 + threadIdx.x;
    if (e >= ETOT) return;
    int s, d;
    if (e < E_) { s = ei[e]; d = ei[E_ + e]; }
    else        { s = e - E_; d = s; }
    int pos = atomicAdd(cursor + d, 1);
    srcs[pos] = s;
    dstp[pos] = d;
    pose[e] = pos;
}

// ---------------- rank scan: rnk[pos] = exclusive prefix of (srcs[pos]!=dstp[pos]) over ETOT
__global__ __launch_bounds__(256) void scanA2_kernel(const int* __restrict__ srcs, const int* __restrict__ dstp,
                                                     int* __restrict__ rnk, int* __restrict__ bsum2) {
    __shared__ int sm[256];
    int tid = threadIdx.x;
    int base = blockIdx.x * 1024 + tid * 4;
    int v[4];
#pragma unroll
    for (int i = 0; i < 4; i++) {
        int p = base + i;
        v[i] = (p < ETOT && srcs[p] != dstp[p]) ? 1 : 0;
    }
    int incl1 = v[0] + v[1], incl2 = incl1 + v[2], incl3 = incl2 + v[3];
    sm[tid] = incl3;
    __syncthreads();
    for (int o = 1; o < 256; o <<= 1) {
        int t = (tid >= o) ? sm[tid - o] : 0;
        __syncthreads();
        sm[tid] += t;
        __syncthreads();
    }
    int prev = tid ? sm[tid - 1] : 0;
    int incl[4] = {v[0], incl1, incl2, incl3};
#pragma unroll
    for (int i = 0; i < 4; i++) {
        int p = base + i;
        if (p < ETOT) rnk[p] = prev + incl[i] - v[i];
    }
    if (tid == 255) bsum2[blockIdx.x] = sm[255];
}

__global__ __launch_bounds__(256) void scanC2_kernel(int* __restrict__ rnk, const int* __restrict__ bsum2) {
    int p = blockIdx.x * 256 + threadIdx.x;
    if (p < ETOT) rnk[p] += bsum2[p >> 10];
}

// compacted per-rank arrays (real edges only, CSR order)
__global__ __launch_bounds__(256) void compact_kernel(const int* __restrict__ srcs, const int* __restrict__ dstp,
                                                      const int* __restrict__ rnk,
                                                      int* __restrict__ srcs_c, int* __restrict__ dstp_c,
                                                      int* __restrict__ posr_c) {
    int pos = blockIdx.x * 256 + threadIdx.x;
    if (pos >= ETOT) return;
    int s = srcs[pos], d = dstp[pos];
    if (s != d) {
        int rk = rnk[pos];
        srcs_c[rk] = s;
        dstp_c[rk] = d;
        posr_c[rk] = pos;
    }
}

// ---------------- node GEMM: split-bf16 3-pass MFMA (fp32-accurate), m97 structure.
#define BM 128

__global__ __launch_bounds__(256, 4) void mfma_gemm_node(
    const short* __restrict__ Ahi_g, const short* __restrict__ Alo_g,
    const short* __restrict__ Bhi_g, const short* __restrict__ Blo_g,
    float* __restrict__ C0, short* __restrict__ C0b, short* __restrict__ C1b,
    const float* __restrict__ bias0, const float* __restrict__ bias1,
    int M, int K) {
    __shared__ short Ah[BM * 32];
    __shared__ short Bh[BM * 32];
    __shared__ short Al[BM * 32];
    __shared__ short Bl[BM * 32];

    const int v = xcd_swz(blockIdx.x, gridDim.x);
    const int n0 = (v & 3) * BM;
    const int m0 = (v >> 2) * BM;
    const int tid = threadIdx.x;
    const int wave = tid >> 6, lane = tid & 63;
    const int wm = (wave >> 1) << 6, wn = (wave & 1) << 6;
    const int r = lane & 15, q = lane >> 4;
    const int qs = (q ^ ((r >> 1) & 3)) << 3;   // physical chunk (shorts)

    const int srow = (wave << 5) + (lane >> 2);
    const int sch = (lane & 3) << 3;
    int ga0 = m0 + srow;       if (ga0 > M - 1) ga0 = M - 1;
    int ga1 = m0 + srow + 16;  if (ga1 > M - 1) ga1 = M - 1;
    const int offA0 = ga0 * K + sch;
    const int offA1 = ga1 * K + sch;
    const int offB0 = (n0 + srow) * K + sch;
    const int offB1 = (n0 + srow + 16) * K + sch;
    short* lA0 = &Ah[(wave << 5) * 32];
    short* lA1 = lA0 + 16 * 32;
    short* lB0 = &Bh[(wave << 5) * 32];
    short* lB1 = lB0 + 16 * 32;
    short* lAl0 = &Al[(wave << 5) * 32];
    short* lAl1 = lAl0 + 16 * 32;
    short* lBl0 = &Bl[(wave << 5) * 32];
    short* lBl1 = lBl0 + 16 * 32;

    f32x4 acc[4][4];
#pragma unroll
    for (int i = 0; i < 4; i++)
#pragma unroll
        for (int j = 0; j < 4; j++) acc[i][j] = (f32x4){0.f, 0.f, 0.f, 0.f};

    for (int k0 = 0; k0 < K; k0 += 32) {
        gload16(Ahi_g + offA0 + k0, lA0);
        gload16(Ahi_g + offA1 + k0, lA1);
        gload16(Bhi_g + offB0 + k0, lB0);
        gload16(Bhi_g + offB1 + k0, lB1);
        gload16(Alo_g + offA0 + k0, lAl0);
        gload16(Alo_g + offA1 + k0, lAl1);
        gload16(Blo_g + offB0 + k0, lBl0);
        gload16(Blo_g + offB1 + k0, lBl1);
        __syncthreads();   // compiler drains vmcnt before s_barrier

        bf16x8 ah[4], bh[4];
#pragma unroll
        for (int f = 0; f < 4; f++) {
            ah[f] = *(const bf16x8*)(Ah + (wm + f * 16 + r) * 32 + qs);
            bh[f] = *(const bf16x8*)(Bh + (wn + f * 16 + r) * 32 + qs);
        }
#pragma unroll
        for (int fm = 0; fm < 4; fm++)
#pragma unroll
            for (int fn = 0; fn < 4; fn++)
                acc[fm][fn] = __builtin_amdgcn_mfma_f32_16x16x32_bf16(ah[fm], bh[fn], acc[fm][fn], 0, 0, 0);
        bf16x8 t[4];
#pragma unroll
        for (int f = 0; f < 4; f++) t[f] = *(const bf16x8*)(Bl + (wn + f * 16 + r) * 32 + qs);
#pragma unroll
        for (int fm = 0; fm < 4; fm++)
#pragma unroll
            for (int fn = 0; fn < 4; fn++)
                acc[fm][fn] = __builtin_amdgcn_mfma_f32_16x16x32_bf16(ah[fm], t[fn], acc[fm][fn], 0, 0, 0);
#pragma unroll
        for (int f = 0; f < 4; f++) t[f] = *(const bf16x8*)(Al + (wm + f * 16 + r) * 32 + qs);
#pragma unroll
        for (int fm = 0; fm < 4; fm++)
#pragma unroll
            for (int fn = 0; fn < 4; fn++)
                acc[fm][fn] = __builtin_amdgcn_mfma_f32_16x16x32_bf16(t[fm], bh[fn], acc[fm][fn], 0, 0, 0);
        __syncthreads();
    }

    // epilogue: C/D map col=lane&15, row=q*4+reg
    const bool second = (n0 >= 256);
    const int ncol = second ? n0 - 256 : n0;
    const float* bs = second ? bias1 : bias0;
#pragma unroll
    for (int fm = 0; fm < 4; fm++) {
#pragma unroll
        for (int fn = 0; fn < 4; fn++) {
            int col = ncol + wn + fn * 16 + r;
            float bv = bs[col];
#pragma unroll
            for (int g = 0; g < 4; g++) {
                int row = m0 + wm + fm * 16 + q * 4 + g;
                if (row < M) {
                    float vv = acc[fm][fn][g] + bv;
                    size_t o = (size_t)row * 256 + col;
                    if (second) {
                        C1b[o] = f2bf(vv);
                    } else {
                        C0[o] = vv;
                        C0b[o] = f2bf(vv);
                    }
                }
            }
        }
    }
}

// ---------------- float <-> order-preserving uint key for atomicMax
__device__ __forceinline__ unsigned fkey(float f) {
    unsigned u = __float_as_uint(f);
    return (u & 0x80000000u) ? ~u : (u | 0x80000000u);
}
__device__ __forceinline__ float funkey(unsigned key) {
    return (key & 0x80000000u) ? __uint_as_float(key & 0x7fffffffu) : __uint_as_float(~key);
}

// ---------------- FUSED edge GEMM (eattr_bf16 @ We) + leaky_relu + att-dot + segment-max.
// Rank-compacted CSR order (real edges only). No C tile in LDS: the reduction runs
// DIRECTLY from the MFMA accumulator. Each wave's 64x64 quadrant = one head; for each
// (fm,g) the quarter-wave q holds row wm+fm*16+q*4+g with cols fn*16+r in acc[fm][fn][g].
// e-value rounding matches the materialized-bf16 path: bf2f(f2bf(acc)).
__global__ __launch_bounds__(256, 4) void edge_fused_kernel(
    const short* __restrict__ Ag,       // eattrb [E_][64] rank-ordered pre-swizzled
    const short* __restrict__ Bg,       // We layer [256][64] pre-swizzled
    const int* __restrict__ srcs_c, const int* __restrict__ dstp_c, const int* __restrict__ posr_c,
    const short* __restrict__ xlb, const short* __restrict__ xrb,
    const float* __restrict__ att,      // layer att [256]
    float* __restrict__ plog, unsigned* __restrict__ lmaxkey) {
    __shared__ short Ah[128 * 32];      // 8 KB
    __shared__ short Bh[128 * 32];      // 8 KB

    const int v = xcd_swz(blockIdx.x, gridDim.x);
    const int n0 = (v & 1) << 7;
    const int m0 = (v >> 1) << 7;
    const int tid = threadIdx.x;
    const int wave = tid >> 6, lane = tid & 63;
    const int wm = (wave >> 1) << 6, wn = (wave & 1) << 6;
    const int r = lane & 15, q = lane >> 4;
    const int qs = (q ^ ((r >> 1) & 3)) << 3;

    const int srow = (wave << 5) + (lane >> 2);
    const int sch = (lane & 3) << 3;
    int ga0 = m0 + srow;       if (ga0 > E_ - 1) ga0 = E_ - 1;
    int ga1 = m0 + srow + 16;  if (ga1 > E_ - 1) ga1 = E_ - 1;
    const int offA0 = ga0 * 64 + sch;
    const int offA1 = ga1 * 64 + sch;
    const int offB0 = (n0 + srow) * 64 + sch;
    const int offB1 = (n0 + srow + 16) * 64 + sch;
    short* lA0 = &Ah[(wave << 5) * 32];
    short* lA1 = lA0 + 16 * 32;
    short* lB0 = &Bh[(wave << 5) * 32];
    short* lB1 = lB0 + 16 * 32;

    f32x4 acc[4][4];
#pragma unroll
    for (int i = 0; i < 4; i++)
#pragma unroll
        for (int j = 0; j < 4; j++) acc[i][j] = (f32x4){0.f, 0.f, 0.f, 0.f};

#pragma unroll
    for (int k0 = 0; k0 < 64; k0 += 32) {
        gload16(Ag + offA0 + k0, lA0);
        gload16(Ag + offA1 + k0, lA1);
        gload16(Bg + offB0 + k0, lB0);
        gload16(Bg + offB1 + k0, lB1);
        __syncthreads();
        bf16x8 ah[4], bh[4];
#pragma unroll
        for (int f = 0; f < 4; f++) {
            ah[f] = *(const bf16x8*)(Ah + (wm + f * 16 + r) * 32 + qs);
            bh[f] = *(const bf16x8*)(Bh + (wn + f * 16 + r) * 32 + qs);
        }
#pragma unroll
        for (int fm = 0; fm < 4; fm++)
#pragma unroll
            for (int fn = 0; fn < 4; fn++)
                acc[fm][fn] = __builtin_amdgcn_mfma_f32_16x16x32_bf16(ah[fm], bh[fn], acc[fm][fn], 0, 0, 0);
        __syncthreads();
    }

    // direct-from-acc reduction: this wave's quadrant = rows [m0+wm, m0+wm+64) x head hglob
    const int gbase = n0 + wn;          // global col base (multiple of 64)
    const int hglob = gbase >> 6;
    float attv[4];
#pragma unroll
    for (int fn = 0; fn < 4; fn++) attv[fn] = att[gbase + fn * 16 + r];

#pragma unroll
    for (int fm = 0; fm < 4; fm++) {
#pragma unroll
        for (int g = 0; g < 4; g++) {
            int ec = m0 + wm + fm * 16 + (q << 2) + g;
            bool valid = (ec < E_);
            int s = 0, d = 0, pos = 0;
            if (valid) { s = srcs_c[ec]; d = dstp_c[ec]; pos = posr_c[ec]; }
            float partial = 0.f;
#pragma unroll
            for (int fn = 0; fn < 4; fn++) {
                int gcol = gbase + fn * 16 + r;
                float ev = bf2f(f2bf(acc[fm][fn][g]));
                float xa = valid ? bf2f(xlb[(size_t)s * 256 + gcol]) : 0.f;
                float xb = valid ? bf2f(xrb[(size_t)d * 256 + gcol]) : 0.f;
                float m = xa + xb + ev;
                m = (m > 0.f) ? m : 0.2f * m;
                partial += m * attv[fn];
            }
#pragma unroll
            for (int o = 1; o < 16; o <<= 1) partial += __shfl_xor(partial, o, 64);
            if (valid && r == 0) {
                plog[(size_t)pos * 4 + hglob] = partial;
                atomicMax(lmaxkey + (size_t)d * 4 + hglob, fkey(partial));
            }
        }
    }
}

// ---------------- self-loop logits (src=dst=n, erow=loope fp32); writes plog[pose[E_+n]]
__global__ __launch_bounds__(256) void self_logits_kernel(const short* __restrict__ xlb, const short* __restrict__ xrb,
                                                          const float* __restrict__ loope, const float* __restrict__ att,
                                                          const int* __restrict__ pose,
                                                          float* __restrict__ plog, unsigned* __restrict__ lmaxkey) {
    int wid = threadIdx.x >> 6;
    int lane = threadIdx.x & 63;
    int n = blockIdx.x * 4 + wid;
    if (n >= N_) return;
    short4 a = *(const short4*)(xlb + (size_t)n * 256 + lane * 4);
    short4 b = *(const short4*)(xrb + (size_t)n * 256 + lane * 4);
    float4 c = *(const float4*)(loope + lane * 4);
    float4 w = *(const float4*)(att + lane * 4);
    float m0 = bf2f(a.x) + bf2f(b.x) + c.x;
    float m1 = bf2f(a.y) + bf2f(b.y) + c.y;
    float m2 = bf2f(a.z) + bf2f(b.z) + c.z;
    float m3 = bf2f(a.w) + bf2f(b.w) + c.w;
    m0 = (m0 > 0.f) ? m0 : 0.2f * m0;
    m1 = (m1 > 0.f) ? m1 : 0.2f * m1;
    m2 = (m2 > 0.f) ? m2 : 0.2f * m2;
    m3 = (m3 > 0.f) ? m3 : 0.2f * m3;
    float r = m0 * w.x + m1 * w.y + m2 * w.z + m3 * w.w;
#pragma unroll
    for (int o = 1; o < 16; o <<= 1) r += __shfl_xor(r, o, 64);
    int pos = pose[E_ + n];
    if ((lane & 15) == 0) {
        int j = lane >> 4;
        plog[(size_t)pos * 4 + j] = r;
        atomicMax(lmaxkey + (size_t)n * 4 + j, fkey(r));
    }
}

// ---------------- p = exp(plog[pos] - lmax[dstp[pos]]); denom[d] += p (all linear)
__global__ __launch_bounds__(256) void pden_kernel(const int* __restrict__ dstp, float* __restrict__ plog,
                                                   const unsigned* __restrict__ lmaxkey, float* __restrict__ denom) {
    int pos = blockIdx.x * 256 + threadIdx.x;
    if (pos >= ETOT) return;
    int d = dstp[pos];
    float4 lg = *(const float4*)(plog + (size_t)pos * 4);
    uint4 km = *(const uint4*)(lmaxkey + (size_t)d * 4);
    float p0 = expf(lg.x - funkey(km.x));
    float p1 = expf(lg.y - funkey(km.y));
    float p2 = expf(lg.z - funkey(km.z));
    float p3 = expf(lg.w - funkey(km.w));
    *(float4*)(plog + (size_t)pos * 4) = make_float4(p0, p1, p2, p3);
    atomicAdd(denom + (size_t)d * 4 + 0, p0);
    atomicAdd(denom + (size_t)d * 4 + 1, p1);
    atomicAdd(denom + (size_t)d * 4 + 2, p2);
    atomicAdd(denom + (size_t)d * 4 + 3, p3);
}

// ---------------- alpha[pos] = plog[pos] / denom[dstp[pos]] (all linear)
__global__ __launch_bounds__(256) void alpha_kernel(const int* __restrict__ dstp,
                                                    const float* __restrict__ plog, const float* __restrict__ denom,
                                                    float* __restrict__ alpha) {
    int pos = blockIdx.x * 256 + threadIdx.x;
    if (pos >= ETOT) return;
    int d = dstp[pos];
    float4 dn = *(const float4*)(denom + (size_t)d * 4);
    float4 p = *(const float4*)(plog + (size_t)pos * 4);
    float4 al;
    al.x = p.x / (dn.x + 1e-16f);
    al.y = p.y / (dn.y + 1e-16f);
    al.z = p.z / (dn.z + 1e-16f);
    al.w = p.w / (dn.w + 1e-16f);
    *(float4*)(alpha + (size_t)pos * 4) = al;
}

// ---------------- CSR aggregation, wave-per-node, float4 lanes.
__global__ __launch_bounds__(256) void agg_kernel(const float* __restrict__ xl, const float* __restrict__ alpha,
                                                  const int* __restrict__ off, const int* __restrict__ srcs,
                                                  const float* __restrict__ bias,
                                                  float* __restrict__ xf32, short* __restrict__ xhi,
                                                  short* __restrict__ xlo) {
    int wid = threadIdx.x >> 6, lane = threadIdx.x & 63;
    int d = blockIdx.x * 4 + wid;
    if (d >= N_) return;
    int s0 = off[d], s1 = off[d + 1];
    int col = lane << 2;
    int h = lane >> 4;
    float4 acc = make_float4(0.f, 0.f, 0.f, 0.f);
    int i = s0;
    for (; i + 2 <= s1; i += 2) {
        int a0 = srcs[i], a1 = srcs[i + 1];
        float w0 = alpha[(size_t)i * 4 + h];
        float w1 = alpha[(size_t)(i + 1) * 4 + h];
        float4 x0 = *(const float4*)(xl + (size_t)a0 * 256 + col);
        float4 x1 = *(const float4*)(xl + (size_t)a1 * 256 + col);
        acc.x += w0 * x0.x + w1 * x1.x;
        acc.y += w0 * x0.y + w1 * x1.y;
        acc.z += w0 * x0.z + w1 * x1.z;
        acc.w += w0 * x0.w + w1 * x1.w;
    }
    if (i < s1) {
        int a0 = srcs[i];
        float w0 = alpha[(size_t)i * 4 + h];
        float4 x0 = *(const float4*)(xl + (size_t)a0 * 256 + col);
        acc.x += w0 * x0.x;
        acc.y += w0 * x0.y;
        acc.z += w0 * x0.z;
        acc.w += w0 * x0.w;
    }
    float4 bv = *(const float4*)(bias + col);
    float4 v;
    v.x = acc.x + bv.x; v.x = v.x > 0.f ? v.x : 0.f;
    v.y = acc.y + bv.y; v.y = v.y > 0.f ? v.y : 0.f;
    v.z = acc.z + bv.z; v.z = v.z > 0.f ? v.z : 0.f;
    v.w = acc.w + bv.w; v.w = v.w > 0.f ? v.w : 0.f;
    if (xf32) *(float4*)(xf32 + (size_t)d * 256 + col) = v;
    if (xhi) {
        int c = (lane >> 1) & 3, s = (d >> 1) & 3;
        size_t o = (size_t)d * 256 + (col & ~31) + ((c ^ s) << 3) + (col & 7);
        float f[4] = {v.x, v.y, v.z, v.w};
        short4 hh, ll;
        short* ph = (short*)&hh;
        short* pl = (short*)&ll;
#pragma unroll
        for (int j = 0; j < 4; j++) {
            ph[j] = f2bf(f[j]);
            pl[j] = f2bf(f[j] - bf2f(ph[j]));
        }
        *(short4*)(xhi + o) = hh;
        *(short4*)(xlo + o) = ll;
    }
}

// ---------------- per-graph mean pool + 2-layer MLP head
__device__ __forceinline__ int lbound(const int* __restrict__ a, int n, int v) {
    int lo = 0, hi = n;
    while (lo < hi) { int mid = (lo + hi) >> 1; if (a[mid] < v) lo = mid + 1; else hi = mid; }
    return lo;
}

__global__ __launch_bounds__(256) void pool_mlp_kernel(const float* __restrict__ x, const int* __restrict__ batch,
                                                       const float* __restrict__ Wp1, const float* __restrict__ bp1,
                                                       const float* __restrict__ Wp2, const float* __restrict__ bp2,
                                                       float* __restrict__ out) {
    int g = blockIdx.x;
    int t = threadIdx.x;
    int lo = lbound(batch, N_, g);
    int hi = lbound(batch, N_, g + 1);
    float sum = 0.f;
    for (int n = lo; n < hi; n++) sum += x[(size_t)n * 256 + t];
    int cnt = hi - lo;
    float pooled = sum / (float)(cnt > 1 ? cnt : 1);
    __shared__ float sp[256];
    __shared__ float sh[128];
    __shared__ float sw[4];
    sp[t] = pooled;
    __syncthreads();
    if (t < 128) {
        float a = bp1[t];
        for (int k = 0; k < 256; k++) a += sp[k] * Wp1[k * 128 + t];
        sh[t] = a > 0.f ? a : 0.f;
    }
    __syncthreads();
    float v = (t < 128) ? sh[t] * Wp2[t] : 0.f;
#pragma unroll
    for (int o = 32; o; o >>= 1) v += __shfl_xor(v, o, 64);
    if ((t & 63) == 0) sw[t >> 6] = v;
    __syncthreads();
    if (t == 0) out[g] = sw[0] + sw[1] + sw[2] + sw[3] + bp2[0];
}

// ---------------- workspace layout (bytes), total ~375 MB
#define XHI_OFF  ((size_t)0)                               // 51.2 MB
#define XLO_OFF  (XHI_OFF + (size_t)N_ * 256 * 2)          // 51.2 MB
#define W0_OFF   ((size_t)0)                               // overlays XHI/XLO
#define XL_OFF   (XLO_OFF + (size_t)N_ * 256 * 2)          // xl fp32 102.4 MB
#define XLB_OFF  (XL_OFF + (size_t)N_ * 256 * 4)           // xl bf16  51.2 MB
#define XRB_OFF  (XLB_OFF + (size_t)N_ * 256 * 2)          // xr bf16  51.2 MB
#define LG_OFF   (XRB_OFF + (size_t)N_ * 256 * 2)          // plog 6.4 MB
#define AL_OFF   (LG_OFF + (size_t)ETOT * 4 * 4)           // alpha_csr 6.4 MB
#define LM_OFF   (AL_OFF + (size_t)ETOT * 4 * 4)
#define DN_OFF   (LM_OFF + (size_t)N_ * 4 * 4)
#define DG_OFF   (DN_OFF + (size_t)N_ * 4 * 4)
#define OF_OFF   (DG_OFF + (size_t)N_ * 4)
#define CU_OFF   (OF_OFF + (size_t)(N_ + 32) * 4)
#define SR_OFF   (CU_OFF + (size_t)N_ * 4)
#define DP_OFF   (SR_OFF + (size_t)ETOT * 4)
#define PE_OFF   (DP_OFF + (size_t)ETOT * 4)
#define RN_OFF   (PE_OFF + (size_t)ETOT * 4)               // rnk [ETOT]
#define SC_OFF   (RN_OFF + (size_t)ETOT * 4)               // srcs_c [E_]
#define DC_OFF   (SC_OFF + (size_t)E_ * 4)                 // dstp_c [E_]
#define PC_OFF   (DC_OFF + (size_t)E_ * 4)                 // posr_c [E_]
#define BS_OFF   (PC_OFF + (size_t)E_ * 4)                 // bsum (scan1)
#define BS2_OFF  (BS_OFF + (size_t)512)                    // bsum2 (scan2) 391*4
#define MS_OFF   (BS2_OFF + (size_t)2048)
#define LE_OFF   (MS_OFF + (size_t)256)
#define WCH_OFF  (LE_OFF + (size_t)2048)
#define WCL_OFF  (WCH_OFF + (size_t)3 * 512 * 256 * 2)
#define WEH_OFF  (WCL_OFF + (size_t)3 * 512 * 256 * 2)
#define EAT_OFF  (WEH_OFF + (size_t)3 * 256 * 64 * 2)      // eattrb rank-ordered 38.4 MB

extern "C" void kernel_launch(void* const* d_in, const int* in_sizes, int n_in,
                              void* d_out, int out_size, void* d_ws, size_t ws_size,
                              hipStream_t stream) {
    const float* x     = (const float*)d_in[0];
    const int*   ei    = (const int*)d_in[1];
    const float* eattr = (const float*)d_in[2];
    const int*   batch = (const int*)d_in[3];
    const float* Wl    = (const float*)d_in[4];
    const float* bl    = (const float*)d_in[5];
    const float* Wr    = (const float*)d_in[6];
    const float* br    = (const float*)d_in[7];
    const float* We    = (const float*)d_in[8];
    const float* att   = (const float*)d_in[9];
    const float* bias  = (const float*)d_in[10];
    const float* Wp1   = (const float*)d_in[11];
    const float* bp1   = (const float*)d_in[12];
    const float* Wp2   = (const float*)d_in[13];
    const float* bp2   = (const float*)d_in[14];

    char* ws = (char*)d_ws;
    short*    xhi     = (short*)(ws + XHI_OFF);
    short*    xlo     = (short*)(ws + XLO_OFF);
    float*    w0      = (float*)(ws + W0_OFF);
    float*    xl      = (float*)(ws + XL_OFF);
    short*    xlb     = (short*)(ws + XLB_OFF);
    short*    xrb     = (short*)(ws + XRB_OFF);
    float*    plog    = (float*)(ws + LG_OFF);
    float*    alpha   = (float*)(ws + AL_OFF);
    unsigned* lmaxkey = (unsigned*)(ws + LM_OFF);
    float*    denom   = (float*)(ws + DN_OFF);
    int*      deg     = (int*)(ws + DG_OFF);
    int*      off     = (int*)(ws + OF_OFF);
    int*      cursor  = (int*)(ws + CU_OFF);
    int*      srcs    = (int*)(ws + SR_OFF);
    int*      dstp    = (int*)(ws + DP_OFF);
    int*      pose    = (int*)(ws + PE_OFF);
    int*      rnk     = (int*)(ws + RN_OFF);
    int*      srcs_c  = (int*)(ws + SC_OFF);
    int*      dstp_c  = (int*)(ws + DC_OFF);
    int*      posr_c  = (int*)(ws + PC_OFF);
    int*      bsum    = (int*)(ws + BS_OFF);
    int*      bsum2   = (int*)(ws + BS2_OFF);
    float*    meansum = (float*)(ws + MS_OFF);
    float*    loope   = (float*)(ws + LE_OFF);
    short*    wcatH   = (short*)(ws + WCH_OFF);
    short*    wcatL   = (short*)(ws + WCL_OFF);
    short*    weH     = (short*)(ws + WEH_OFF);
    short*    eattrb  = (short*)(ws + EAT_OFF);

    // setup
    hipMemsetAsync(meansum, 0, 64 * 4, stream);
    hipMemsetAsync(deg, 0, (size_t)N_ * 4, stream);
    mean_kernel<<<512, 256, 0, stream>>>(eattr, meansum);
    prep_wcat_kernel<<<(3 * 512 * 256 + 255) / 256, 256, 0, stream>>>(Wl, Wr, wcatH, wcatL);
    prep_we_kernel<<<(3 * 256 * 64 + 255) / 256, 256, 0, stream>>>(We, weH);
    split_x_kernel<<<(N_ * 32 + 255) / 256, 256, 0, stream>>>(x, xhi, xlo);
    hist_kernel<<<(ETOT + 255) / 256, 256, 0, stream>>>(ei, deg);
    scanA_kernel<<<NB_SCAN, 256, 0, stream>>>(deg, off, bsum);
    scanB_kernel<<<1, 64, 0, stream>>>(bsum, NB_SCAN);
    scanC_kernel<<<(N_ + 255) / 256, 256, 0, stream>>>(off, bsum);
    hipMemcpyAsync(cursor, off, (size_t)N_ * 4, hipMemcpyDeviceToDevice, stream);
    scatter_kernel<<<(ETOT + 255) / 256, 256, 0, stream>>>(ei, cursor, srcs, dstp, pose);
    // rank-compaction of real edges (CSR order, gaps removed)
    scanA2_kernel<<<NB_SCAN2, 256, 0, stream>>>(srcs, dstp, rnk, bsum2);
    scanB_kernel<<<1, 64, 0, stream>>>(bsum2, NB_SCAN2);
    scanC2_kernel<<<(ETOT + 255) / 256, 256, 0, stream>>>(rnk, bsum2);
    compact_kernel<<<(ETOT + 255) / 256, 256, 0, stream>>>(srcs, dstp, rnk, srcs_c, dstp_c, posr_c);
    split_e_kernel<<<(E_ * 8 + 255) / 256, 256, 0, stream>>>(eattr, eattrb, pose, rnk);

    const int mtN = (N_ + BM - 1) / BM;         // 782
    const int nwgN = 4 * mtN;                   // 3128
    const int mtE = (E_ + 127) / 128;           // 2344
    const int nwgE = 2 * mtE;                   // 4688

    for (int l = 0; l < 3; l++) {
        const float* We_l = We + (size_t)l * 64 * 256;
        const float* att_l = att + (size_t)l * 256;
        loope_kernel<<<1, 256, 0, stream>>>(meansum, We_l, loope);
        // xl (fp32+bf16) | xr (bf16 only), fp32-split 3-pass path
        mfma_gemm_node<<<nwgN, 256, 0, stream>>>(
            xhi, xlo, wcatH + (size_t)l * 512 * 256, wcatL + (size_t)l * 512 * 256,
            xl, xlb, xrb, bl + (size_t)l * 256, br + (size_t)l * 256, N_, 256);
        hipMemsetAsync(lmaxkey, 0, (size_t)N_ * 4 * 4, stream);
        hipMemsetAsync(denom, 0, (size_t)N_ * 4 * 4, stream);
        edge_fused_kernel<<<nwgE, 256, 0, stream>>>(
            eattrb, weH + (size_t)l * 256 * 64, srcs_c, dstp_c, posr_c, xlb, xrb, att_l, plog, lmaxkey);
        self_logits_kernel<<<(N_ + 3) / 4, 256, 0, stream>>>(xlb, xrb, loope, att_l, pose, plog, lmaxkey);
        pden_kernel<<<(ETOT + 255) / 256, 256, 0, stream>>>(dstp, plog, lmaxkey, denom);
        alpha_kernel<<<(ETOT + 255) / 256, 256, 0, stream>>>(dstp, plog, denom, alpha);
        // layers 0,1: write next layer's hi/lo splits (no fp32); layer 2: fp32 for pool
        agg_kernel<<<(N_ + 3) / 4, 256, 0, stream>>>(
            xl, alpha, off, srcs, bias + (size_t)l * 256,
            (l == 2) ? w0 : nullptr,
            (l < 2) ? xhi : nullptr,
            (l < 2) ? xlo : nullptr);
    }

    pool_mlp_kernel<<<G_, 256, 0, stream>>>(w0, batch, Wp1, bp1, Wp2, bp2, (float*)d_out);
}

// Round 5
// 1629.624 us; speedup vs baseline: 1.2635x; 1.2635x over previous
//
#include <hip/hip_runtime.h>
#include <hip/hip_bf16.h>

#define N_ 100000
#define E_ 300000
#define ETOT 400000
#define G_ 2048
#define NB_SCAN 98        // ceil(N_/1024)
#define NB_SCAN2 391      // ceil(ETOT/1024)

typedef __attribute__((ext_vector_type(8))) short bf16x8;
typedef __attribute__((ext_vector_type(4))) float f32x4;

__device__ __forceinline__ short f2bf(float f) {
    __hip_bfloat16 h = __float2bfloat16(f);
    return *reinterpret_cast<short*>(&h);
}
__device__ __forceinline__ float bf2f(short s) {
    __hip_bfloat16 h = *reinterpret_cast<__hip_bfloat16*>(&s);
    return __bfloat162float(h);
}

// async global->LDS, 16B per lane. LDS dest is wave-uniform base + lane*16.
typedef __attribute__((address_space(1))) void* gas_ptr;
typedef __attribute__((address_space(3))) void* las_ptr;
__device__ __forceinline__ void gload16(const void* g, void* l) {
    __builtin_amdgcn_global_load_lds((gas_ptr)g, (las_ptr)l, 16, 0, 0);
}

// bijective XCD swizzle (m204)
__device__ __forceinline__ int xcd_swz(int bid, int nwg) {
    int q = nwg >> 3, rr = nwg & 7;
    int xcd = bid & 7, i = bid >> 3;
    return (xcd < rr) ? xcd * (q + 1) + i : rr * (q + 1) + (xcd - rr) * q + i;
}

// ---------------- mean of edge_attr over rows -> meansum[64] (sum; divide later)
__global__ __launch_bounds__(256) void mean_kernel(const float* __restrict__ ea, float* __restrict__ meansum) {
    __shared__ float s[256];
    int tid = threadIdx.x;
    int col = tid & 63, rg = tid >> 6;
    float acc = 0.f;
    for (long long row = (long long)blockIdx.x * 4 + rg; row < E_; row += (long long)gridDim.x * 4)
        acc += ea[row * 64 + col];
    s[tid] = acc;
    __syncthreads();
    if (tid < 64) atomicAdd(meansum + tid, s[tid] + s[tid + 64] + s[tid + 128] + s[tid + 192]);
}

// ---------------- loop_e[c] = (meansum/E) @ We_l
__global__ __launch_bounds__(256) void loope_kernel(const float* __restrict__ meansum,
                                                    const float* __restrict__ We_l,
                                                    float* __restrict__ loope) {
    int c = threadIdx.x;
    float acc = 0.f;
    const float invE = 1.0f / (float)E_;
    for (int k = 0; k < 64; k++) acc += (meansum[k] * invE) * We_l[k * 256 + c];
    loope[c] = acc;
}

// swizzled column within 32-col window: chunk c -> c ^ ((row>>1)&3)
__device__ __forceinline__ int swz_col(int row, int k) {
    int c = (k >> 3) & 3;
    int s = (row >> 1) & 3;
    return (k & ~31) | ((c ^ s) << 3) | (k & 7);
}

// ---------------- weight prep: split fp32 -> (hi,lo) bf16, transposed to [n][k], pre-swizzled
__global__ __launch_bounds__(256) void prep_wcat_kernel(const float* __restrict__ Wl, const float* __restrict__ Wr,
                                                        short* __restrict__ hi, short* __restrict__ lo) {
    int idx = blockIdx.x * 256 + threadIdx.x;
    if (idx >= 3 * 512 * 256) return;
    int l = idx / (512 * 256);
    int rem = idx % (512 * 256);
    int n = rem >> 8, k = rem & 255;
    float v = (n < 256) ? Wl[((size_t)l * 256 + k) * 256 + n]
                        : Wr[((size_t)l * 256 + k) * 256 + (n - 256)];
    short h = f2bf(v);
    size_t o = (size_t)l * 512 * 256 + (size_t)n * 256 + swz_col(n, k);
    hi[o] = h;
    lo[o] = f2bf(v - bf2f(h));
}

__global__ __launch_bounds__(256) void prep_we_kernel(const float* __restrict__ We,
                                                      short* __restrict__ hi) {
    int idx = blockIdx.x * 256 + threadIdx.x;
    if (idx >= 3 * 256 * 64) return;
    int l = idx / (256 * 64);
    int rem = idx % (256 * 64);
    int n = rem >> 6, k = rem & 63;
    float v = We[((size_t)l * 64 + k) * 256 + n];
    hi[(size_t)l * 256 * 64 + (size_t)n * 64 + swz_col(n, k)] = f2bf(v);
}

// ---------------- split x fp32 [N_][256] -> pre-swizzled bf16 hi/lo
__global__ __launch_bounds__(256) void split_x_kernel(const float* __restrict__ in,
                                                      short* __restrict__ hi, short* __restrict__ lo) {
    int idx = blockIdx.x * 256 + threadIdx.x;
    if (idx >= N_ * 32) return;
    int gm = idx >> 5, cw = idx & 31;
    int c = cw & 3, win = cw >> 2;
    int s = (gm >> 1) & 3;
    const float* src = in + (size_t)gm * 256 + (win << 5) + (c << 3);
    float4 f0 = *(const float4*)src;
    float4 f1 = *(const float4*)(src + 4);
    float f[8] = {f0.x, f0.y, f0.z, f0.w, f1.x, f1.y, f1.z, f1.w};
    bf16x8 vh, vl;
#pragma unroll
    for (int j = 0; j < 8; j++) {
        short h = f2bf(f[j]);
        vh[j] = h;
        vl[j] = f2bf(f[j] - bf2f(h));
    }
    size_t o = (size_t)gm * 256 + (win << 5) + ((c ^ s) << 3);
    *(bf16x8*)(hi + o) = vh;
    *(bf16x8*)(lo + o) = vl;
}

// ---------------- eattr fp32 [E_][64] -> bf16, permuted to RANK (compacted CSR) order, pre-swizzled
__global__ __launch_bounds__(256) void split_e_kernel(const float* __restrict__ in, short* __restrict__ hi,
                                                      const int* __restrict__ pose, const int* __restrict__ rnk) {
    int idx = blockIdx.x * 256 + threadIdx.x;
    if (idx >= E_ * 8) return;
    int e = idx >> 3, cw = idx & 7;
    int c = cw & 3, win = cw >> 2;
    int rk = rnk[pose[e]];
    int s = (rk >> 1) & 3;
    const float* src = in + (size_t)e * 64 + (win << 5) + (c << 3);
    float4 f0 = *(const float4*)src;
    float4 f1 = *(const float4*)(src + 4);
    float f[8] = {f0.x, f0.y, f0.z, f0.w, f1.x, f1.y, f1.z, f1.w};
    bf16x8 vh;
#pragma unroll
    for (int j = 0; j < 8; j++) vh[j] = f2bf(f[j]);
    *(bf16x8*)(hi + (size_t)rk * 64 + (win << 5) + ((c ^ s) << 3)) = vh;
}

// ---------------- CSR build over dst (self loops e>=E_ have dst = e-E_)
__global__ __launch_bounds__(256) void hist_kernel(const int* __restrict__ ei, int* __restrict__ deg) {
    int e = blockIdx.x * 256 + threadIdx.x;
    if (e >= ETOT) return;
    int d = (e < E_) ? ei[E_ + e] : (e - E_);
    atomicAdd(deg + d, 1);
}

__global__ __launch_bounds__(256) void scanA_kernel(const int* __restrict__ deg, int* __restrict__ off,
                                                    int* __restrict__ bsum) {
    __shared__ int s[256];
    int tid = threadIdx.x;
    int base = blockIdx.x * 1024 + tid * 4;
    int v[4];
#pragma unroll
    for (int i = 0; i < 4; i++) v[i] = (base + i < N_) ? deg[base + i] : 0;
    v[1] += v[0]; v[2] += v[1]; v[3] += v[2];
    s[tid] = v[3];
    __syncthreads();
    for (int o = 1; o < 256; o <<= 1) {
        int t = (tid >= o) ? s[tid - o] : 0;
        __syncthreads();
        s[tid] += t;
        __syncthreads();
    }
    int prev = tid ? s[tid - 1] : 0;
#pragma unroll
    for (int i = 0; i < 4; i++)
        if (base + i < N_) off[base + i + 1] = prev + v[i];
    if (tid == 255) bsum[blockIdx.x] = s[255];
}

__global__ void scanB_kernel(int* __restrict__ bsum, int n) {
    if (threadIdx.x == 0) {
        int run = 0;
        for (int i = 0; i < n; i++) { int t = bsum[i]; bsum[i] = run; run += t; }
    }
}

__global__ __launch_bounds__(256) void scanC_kernel(int* __restrict__ off, const int* __restrict__ bsum) {
    int i = blockIdx.x * 256 + threadIdx.x;
    if (i < N_) {
        off[i + 1] += bsum[i >> 10];
        if (i == 0) off[0] = 0;
    }
}

// scatter: srcs[pos]=src; dstp[pos]=dst; pose[e]=pos
__global__ __launch_bounds__(256) void scatter_kernel(const int* __restrict__ ei, int* __restrict__ cursor,
                                                      int* __restrict__ srcs, int* __restrict__ dstp,
                                                      int* __restrict__ pose) {
    int e = blockIdx.x * 256 + threadIdx.x;
    if (e >= ETOT) return;
    int s, d;
    if (e < E_) { s = ei[e]; d = ei[E_ + e]; }
    else        { s = e - E_; d = s; }
    int pos = atomicAdd(cursor + d, 1);
    srcs[pos] = s;
    dstp[pos] = d;
    pose[e] = pos;
}

// ---------------- rank scan: rnk[pos] = exclusive prefix of (srcs[pos]!=dstp[pos]) over ETOT
__global__ __launch_bounds__(256) void scanA2_kernel(const int* __restrict__ srcs, const int* __restrict__ dstp,
                                                     int* __restrict__ rnk, int* __restrict__ bsum2) {
    __shared__ int sm[256];
    int tid = threadIdx.x;
    int base = blockIdx.x * 1024 + tid * 4;
    int v[4];
#pragma unroll
    for (int i = 0; i < 4; i++) {
        int p = base + i;
        v[i] = (p < ETOT && srcs[p] != dstp[p]) ? 1 : 0;
    }
    int incl1 = v[0] + v[1], incl2 = incl1 + v[2], incl3 = incl2 + v[3];
    sm[tid] = incl3;
    __syncthreads();
    for (int o = 1; o < 256; o <<= 1) {
        int t = (tid >= o) ? sm[tid - o] : 0;
        __syncthreads();
        sm[tid] += t;
        __syncthreads();
    }
    int prev = tid ? sm[tid - 1] : 0;
    int incl[4] = {v[0], incl1, incl2, incl3};
#pragma unroll
    for (int i = 0; i < 4; i++) {
        int p = base + i;
        if (p < ETOT) rnk[p] = prev + incl[i] - v[i];
    }
    if (tid == 255) bsum2[blockIdx.x] = sm[255];
}

__global__ __launch_bounds__(256) void scanC2_kernel(int* __restrict__ rnk, const int* __restrict__ bsum2) {
    int p = blockIdx.x * 256 + threadIdx.x;
    if (p < ETOT) rnk[p] += bsum2[p >> 10];
}

// compacted per-rank arrays (real edges only, CSR order)
__global__ __launch_bounds__(256) void compact_kernel(const int* __restrict__ srcs, const int* __restrict__ dstp,
                                                      const int* __restrict__ rnk,
                                                      int* __restrict__ srcs_c, int* __restrict__ dstp_c,
                                                      int* __restrict__ posr_c) {
    int pos = blockIdx.x * 256 + threadIdx.x;
    if (pos >= ETOT) return;
    int s = srcs[pos], d = dstp[pos];
    if (s != d) {
        int rk = rnk[pos];
        srcs_c[rk] = s;
        dstp_c[rk] = d;
        posr_c[rk] = pos;
    }
}

// ---------------- node GEMM: split-bf16 3-pass MFMA (fp32-accurate), m97 structure.
#define BM 128

__global__ __launch_bounds__(256, 4) void mfma_gemm_node(
    const short* __restrict__ Ahi_g, const short* __restrict__ Alo_g,
    const short* __restrict__ Bhi_g, const short* __restrict__ Blo_g,
    float* __restrict__ C0, short* __restrict__ C0b, short* __restrict__ C1b,
    const float* __restrict__ bias0, const float* __restrict__ bias1,
    int M, int K) {
    __shared__ short Ah[BM * 32];
    __shared__ short Bh[BM * 32];
    __shared__ short Al[BM * 32];
    __shared__ short Bl[BM * 32];

    const int v = xcd_swz(blockIdx.x, gridDim.x);
    const int n0 = (v & 3) * BM;
    const int m0 = (v >> 2) * BM;
    const int tid = threadIdx.x;
    const int wave = tid >> 6, lane = tid & 63;
    const int wm = (wave >> 1) << 6, wn = (wave & 1) << 6;
    const int r = lane & 15, q = lane >> 4;
    const int qs = (q ^ ((r >> 1) & 3)) << 3;   // physical chunk (shorts)

    const int srow = (wave << 5) + (lane >> 2);
    const int sch = (lane & 3) << 3;
    int ga0 = m0 + srow;       if (ga0 > M - 1) ga0 = M - 1;
    int ga1 = m0 + srow + 16;  if (ga1 > M - 1) ga1 = M - 1;
    const int offA0 = ga0 * K + sch;
    const int offA1 = ga1 * K + sch;
    const int offB0 = (n0 + srow) * K + sch;
    const int offB1 = (n0 + srow + 16) * K + sch;
    short* lA0 = &Ah[(wave << 5) * 32];
    short* lA1 = lA0 + 16 * 32;
    short* lB0 = &Bh[(wave << 5) * 32];
    short* lB1 = lB0 + 16 * 32;
    short* lAl0 = &Al[(wave << 5) * 32];
    short* lAl1 = lAl0 + 16 * 32;
    short* lBl0 = &Bl[(wave << 5) * 32];
    short* lBl1 = lBl0 + 16 * 32;

    f32x4 acc[4][4];
#pragma unroll
    for (int i = 0; i < 4; i++)
#pragma unroll
        for (int j = 0; j < 4; j++) acc[i][j] = (f32x4){0.f, 0.f, 0.f, 0.f};

    for (int k0 = 0; k0 < K; k0 += 32) {
        gload16(Ahi_g + offA0 + k0, lA0);
        gload16(Ahi_g + offA1 + k0, lA1);
        gload16(Bhi_g + offB0 + k0, lB0);
        gload16(Bhi_g + offB1 + k0, lB1);
        gload16(Alo_g + offA0 + k0, lAl0);
        gload16(Alo_g + offA1 + k0, lAl1);
        gload16(Blo_g + offB0 + k0, lBl0);
        gload16(Blo_g + offB1 + k0, lBl1);
        __syncthreads();   // compiler drains vmcnt before s_barrier

        bf16x8 ah[4], bh[4];
#pragma unroll
        for (int f = 0; f < 4; f++) {
            ah[f] = *(const bf16x8*)(Ah + (wm + f * 16 + r) * 32 + qs);
            bh[f] = *(const bf16x8*)(Bh + (wn + f * 16 + r) * 32 + qs);
        }
#pragma unroll
        for (int fm = 0; fm < 4; fm++)
#pragma unroll
            for (int fn = 0; fn < 4; fn++)
                acc[fm][fn] = __builtin_amdgcn_mfma_f32_16x16x32_bf16(ah[fm], bh[fn], acc[fm][fn], 0, 0, 0);
        bf16x8 t[4];
#pragma unroll
        for (int f = 0; f < 4; f++) t[f] = *(const bf16x8*)(Bl + (wn + f * 16 + r) * 32 + qs);
#pragma unroll
        for (int fm = 0; fm < 4; fm++)
#pragma unroll
            for (int fn = 0; fn < 4; fn++)
                acc[fm][fn] = __builtin_amdgcn_mfma_f32_16x16x32_bf16(ah[fm], t[fn], acc[fm][fn], 0, 0, 0);
#pragma unroll
        for (int f = 0; f < 4; f++) t[f] = *(const bf16x8*)(Al + (wm + f * 16 + r) * 32 + qs);
#pragma unroll
        for (int fm = 0; fm < 4; fm++)
#pragma unroll
            for (int fn = 0; fn < 4; fn++)
                acc[fm][fn] = __builtin_amdgcn_mfma_f32_16x16x32_bf16(t[fm], bh[fn], acc[fm][fn], 0, 0, 0);
        __syncthreads();
    }

    // epilogue: C/D map col=lane&15, row=q*4+reg
    const bool second = (n0 >= 256);
    const int ncol = second ? n0 - 256 : n0;
    const float* bs = second ? bias1 : bias0;
#pragma unroll
    for (int fm = 0; fm < 4; fm++) {
#pragma unroll
        for (int fn = 0; fn < 4; fn++) {
            int col = ncol + wn + fn * 16 + r;
            float bv = bs[col];
#pragma unroll
            for (int g = 0; g < 4; g++) {
                int row = m0 + wm + fm * 16 + q * 4 + g;
                if (row < M) {
                    float vv = acc[fm][fn][g] + bv;
                    size_t o = (size_t)row * 256 + col;
                    if (second) {
                        C1b[o] = f2bf(vv);
                    } else {
                        C0[o] = vv;
                        C0b[o] = f2bf(vv);
                    }
                }
            }
        }
    }
}

// ---------------- FUSED edge GEMM (eattr_bf16 @ We) + leaky_relu + att-dot.
// Rank-compacted CSR order (real edges only). C tile staged bf16 in LDS (round-2
// structure: coalesced short4 gathers in the reduce), with the GEMM staging buffers
// UNIONED into the same LDS (16KB stage phase / 33.8KB Ct phase, barrier-separated)
// -> 4 blocks/CU. No atomics: plog writes only (near-linear via monotone posr_c);
// segment max/sum handled by softmax_node_kernel.
__global__ __launch_bounds__(256, 4) void edge_fused_kernel(
    const short* __restrict__ Ag,       // eattrb [E_][64] rank-ordered pre-swizzled
    const short* __restrict__ Bg,       // We layer [256][64] pre-swizzled
    const int* __restrict__ srcs_c, const int* __restrict__ dstp_c, const int* __restrict__ posr_c,
    const short* __restrict__ xlb, const short* __restrict__ xrb,
    const float* __restrict__ att,      // layer att [256]
    float* __restrict__ plog) {
    __shared__ short smem[128 * 132];   // union: {Ah,Bh} then Ct
    short* Ah = smem;                   // [128*32]
    short* Bh = smem + 128 * 32;        // [128*32]
    short* Ct = smem;                   // [128*132] after barrier

    const int v = xcd_swz(blockIdx.x, gridDim.x);
    const int n0 = (v & 1) << 7;
    const int m0 = (v >> 1) << 7;
    const int tid = threadIdx.x;
    const int wave = tid >> 6, lane = tid & 63;
    const int wm = (wave >> 1) << 6, wn = (wave & 1) << 6;
    const int r = lane & 15, q = lane >> 4;
    const int qs = (q ^ ((r >> 1) & 3)) << 3;

    const int srow = (wave << 5) + (lane >> 2);
    const int sch = (lane & 3) << 3;
    int ga0 = m0 + srow;       if (ga0 > E_ - 1) ga0 = E_ - 1;
    int ga1 = m0 + srow + 16;  if (ga1 > E_ - 1) ga1 = E_ - 1;
    const int offA0 = ga0 * 64 + sch;
    const int offA1 = ga1 * 64 + sch;
    const int offB0 = (n0 + srow) * 64 + sch;
    const int offB1 = (n0 + srow + 16) * 64 + sch;
    short* lA0 = Ah + (wave << 5) * 32;
    short* lA1 = lA0 + 16 * 32;
    short* lB0 = Bh + (wave << 5) * 32;
    short* lB1 = lB0 + 16 * 32;

    f32x4 acc[4][4];
#pragma unroll
    for (int i = 0; i < 4; i++)
#pragma unroll
        for (int j = 0; j < 4; j++) acc[i][j] = (f32x4){0.f, 0.f, 0.f, 0.f};

#pragma unroll
    for (int k0 = 0; k0 < 64; k0 += 32) {
        gload16(Ag + offA0 + k0, lA0);
        gload16(Ag + offA1 + k0, lA1);
        gload16(Bg + offB0 + k0, lB0);
        gload16(Bg + offB1 + k0, lB1);
        __syncthreads();
        bf16x8 ah[4], bh[4];
#pragma unroll
        for (int f = 0; f < 4; f++) {
            ah[f] = *(const bf16x8*)(Ah + (wm + f * 16 + r) * 32 + qs);
            bh[f] = *(const bf16x8*)(Bh + (wn + f * 16 + r) * 32 + qs);
        }
#pragma unroll
        for (int fm = 0; fm < 4; fm++)
#pragma unroll
            for (int fn = 0; fn < 4; fn++)
                acc[fm][fn] = __builtin_amdgcn_mfma_f32_16x16x32_bf16(ah[fm], bh[fn], acc[fm][fn], 0, 0, 0);
        __syncthreads();
    }

    // write C tile to LDS as bf16 (Ah/Bh dead past the barrier above)
#pragma unroll
    for (int fm = 0; fm < 4; fm++)
#pragma unroll
        for (int fn = 0; fn < 4; fn++)
#pragma unroll
            for (int g = 0; g < 4; g++)
                Ct[(wm + fm * 16 + q * 4 + g) * 132 + wn + fn * 16 + r] = f2bf(acc[fm][fn][g]);
    __syncthreads();

    // reduction: wave handles ranks [wave*32, wave*32+32), 2 per iter; short4 gathers
    const int half = lane >> 5;             // rank parity within pair
    const int hsel = (lane >> 4) & 1;       // head within the 128-col tile
    const int sub = lane & 15;
    const int colL = (hsel << 6) + (sub << 2);
    const float4 w = *(const float4*)(att + n0 + colL);
    const int hglob = (n0 >> 6) + hsel;
    for (int it = 0; it < 16; it++) {
        int prow = (wave << 5) + (it << 1) + half;
        int ec = m0 + prow;
        bool valid = (ec < E_);
        int s = 0, d = 0, pos = 0;
        if (valid) { s = srcs_c[ec]; d = dstp_c[ec]; pos = posr_c[ec]; }
        short4 ev = *(const short4*)(Ct + prow * 132 + colL);
        short4 a = valid ? *(const short4*)(xlb + (size_t)s * 256 + n0 + colL) : make_short4(0, 0, 0, 0);
        short4 b = valid ? *(const short4*)(xrb + (size_t)d * 256 + n0 + colL) : make_short4(0, 0, 0, 0);
        float m0v = bf2f(a.x) + bf2f(b.x) + bf2f(ev.x);
        float m1v = bf2f(a.y) + bf2f(b.y) + bf2f(ev.y);
        float m2v = bf2f(a.z) + bf2f(b.z) + bf2f(ev.z);
        float m3v = bf2f(a.w) + bf2f(b.w) + bf2f(ev.w);
        m0v = (m0v > 0.f) ? m0v : 0.2f * m0v;
        m1v = (m1v > 0.f) ? m1v : 0.2f * m1v;
        m2v = (m2v > 0.f) ? m2v : 0.2f * m2v;
        m3v = (m3v > 0.f) ? m3v : 0.2f * m3v;
        float rr = m0v * w.x + m1v * w.y + m2v * w.z + m3v * w.w;
#pragma unroll
        for (int o = 1; o < 16; o <<= 1) rr += __shfl_xor(rr, o, 64);
        if (valid && sub == 0)
            plog[(size_t)pos * 4 + hglob] = rr;
    }
}

// ---------------- self-loop logits (src=dst=n, erow=loope fp32); writes plog[pose[E_+n]]
__global__ __launch_bounds__(256) void self_logits_kernel(const short* __restrict__ xlb, const short* __restrict__ xrb,
                                                          const float* __restrict__ loope, const float* __restrict__ att,
                                                          const int* __restrict__ pose,
                                                          float* __restrict__ plog) {
    int wid = threadIdx.x >> 6;
    int lane = threadIdx.x & 63;
    int n = blockIdx.x * 4 + wid;
    if (n >= N_) return;
    short4 a = *(const short4*)(xlb + (size_t)n * 256 + lane * 4);
    short4 b = *(const short4*)(xrb + (size_t)n * 256 + lane * 4);
    float4 c = *(const float4*)(loope + lane * 4);
    float4 w = *(const float4*)(att + lane * 4);
    float m0 = bf2f(a.x) + bf2f(b.x) + c.x;
    float m1 = bf2f(a.y) + bf2f(b.y) + c.y;
    float m2 = bf2f(a.z) + bf2f(b.z) + c.z;
    float m3 = bf2f(a.w) + bf2f(b.w) + c.w;
    m0 = (m0 > 0.f) ? m0 : 0.2f * m0;
    m1 = (m1 > 0.f) ? m1 : 0.2f * m1;
    m2 = (m2 > 0.f) ? m2 : 0.2f * m2;
    m3 = (m3 > 0.f) ? m3 : 0.2f * m3;
    float r = m0 * w.x + m1 * w.y + m2 * w.z + m3 * w.w;
#pragma unroll
    for (int o = 1; o < 16; o <<= 1) r += __shfl_xor(r, o, 64);
    int pos = pose[E_ + n];
    if ((lane & 15) == 0)
        plog[(size_t)pos * 4 + (lane >> 4)] = r;
}

// ---------------- per-node segment softmax over CSR range: alpha = exp(l-max)/(sum+1e-16)
// Wave per node: 16 sub-lanes x 4 heads. No atomics; max exact; sum order was
// nondeterministic before (atomicAdd), tree order equally valid.
__global__ __launch_bounds__(256) void softmax_node_kernel(const int* __restrict__ off,
                                                           const float* __restrict__ plog,
                                                           float* __restrict__ alpha) {
    int wid = threadIdx.x >> 6, lane = threadIdx.x & 63;
    int d = blockIdx.x * 4 + wid;
    if (d >= N_) return;
    int s0 = off[d], s1 = off[d + 1];
    int sub = lane & 15, h = lane >> 4;
    float mx = -3.4e38f;
    for (int i = s0 + sub; i < s1; i += 16)
        mx = fmaxf(mx, plog[(size_t)i * 4 + h]);
#pragma unroll
    for (int o = 1; o < 16; o <<= 1) mx = fmaxf(mx, __shfl_xor(mx, o, 64));
    float sum = 0.f;
    for (int i = s0 + sub; i < s1; i += 16)
        sum += expf(plog[(size_t)i * 4 + h] - mx);
#pragma unroll
    for (int o = 1; o < 16; o <<= 1) sum += __shfl_xor(sum, o, 64);
    float dn = sum + 1e-16f;
    for (int i = s0 + sub; i < s1; i += 16)
        alpha[(size_t)i * 4 + h] = expf(plog[(size_t)i * 4 + h] - mx) / dn;
}

// ---------------- CSR aggregation, wave-per-node, float4 lanes.
__global__ __launch_bounds__(256) void agg_kernel(const float* __restrict__ xl, const float* __restrict__ alpha,
                                                  const int* __restrict__ off, const int* __restrict__ srcs,
                                                  const float* __restrict__ bias,
                                                  float* __restrict__ xf32, short* __restrict__ xhi,
                                                  short* __restrict__ xlo) {
    int wid = threadIdx.x >> 6, lane = threadIdx.x & 63;
    int d = blockIdx.x * 4 + wid;
    if (d >= N_) return;
    int s0 = off[d], s1 = off[d + 1];
    int col = lane << 2;
    int h = lane >> 4;
    float4 acc = make_float4(0.f, 0.f, 0.f, 0.f);
    int i = s0;
    for (; i + 2 <= s1; i += 2) {
        int a0 = srcs[i], a1 = srcs[i + 1];
        float w0 = alpha[(size_t)i * 4 + h];
        float w1 = alpha[(size_t)(i + 1) * 4 + h];
        float4 x0 = *(const float4*)(xl + (size_t)a0 * 256 + col);
        float4 x1 = *(const float4*)(xl + (size_t)a1 * 256 + col);
        acc.x += w0 * x0.x + w1 * x1.x;
        acc.y += w0 * x0.y + w1 * x1.y;
        acc.z += w0 * x0.z + w1 * x1.z;
        acc.w += w0 * x0.w + w1 * x1.w;
    }
    if (i < s1) {
        int a0 = srcs[i];
        float w0 = alpha[(size_t)i * 4 + h];
        float4 x0 = *(const float4*)(xl + (size_t)a0 * 256 + col);
        acc.x += w0 * x0.x;
        acc.y += w0 * x0.y;
        acc.z += w0 * x0.z;
        acc.w += w0 * x0.w;
    }
    float4 bv = *(const float4*)(bias + col);
    float4 v;
    v.x = acc.x + bv.x; v.x = v.x > 0.f ? v.x : 0.f;
    v.y = acc.y + bv.y; v.y = v.y > 0.f ? v.y : 0.f;
    v.z = acc.z + bv.z; v.z = v.z > 0.f ? v.z : 0.f;
    v.w = acc.w + bv.w; v.w = v.w > 0.f ? v.w : 0.f;
    if (xf32) *(float4*)(xf32 + (size_t)d * 256 + col) = v;
    if (xhi) {
        int c = (lane >> 1) & 3, s = (d >> 1) & 3;
        size_t o = (size_t)d * 256 + (col & ~31) + ((c ^ s) << 3) + (col & 7);
        float f[4] = {v.x, v.y, v.z, v.w};
        short4 hh, ll;
        short* ph = (short*)&hh;
        short* pl = (short*)&ll;
#pragma unroll
        for (int j = 0; j < 4; j++) {
            ph[j] = f2bf(f[j]);
            pl[j] = f2bf(f[j] - bf2f(ph[j]));
        }
        *(short4*)(xhi + o) = hh;
        *(short4*)(xlo + o) = ll;
    }
}

// ---------------- per-graph mean pool + 2-layer MLP head
__device__ __forceinline__ int lbound(const int* __restrict__ a, int n, int v) {
    int lo = 0, hi = n;
    while (lo < hi) { int mid = (lo + hi) >> 1; if (a[mid] < v) lo = mid + 1; else hi = mid; }
    return lo;
}

__global__ __launch_bounds__(256) void pool_mlp_kernel(const float* __restrict__ x, const int* __restrict__ batch,
                                                       const float* __restrict__ Wp1, const float* __restrict__ bp1,
                                                       const float* __restrict__ Wp2, const float* __restrict__ bp2,
                                                       float* __restrict__ out) {
    int g = blockIdx.x;
    int t = threadIdx.x;
    int lo = lbound(batch, N_, g);
    int hi = lbound(batch, N_, g + 1);
    float sum = 0.f;
    for (int n = lo; n < hi; n++) sum += x[(size_t)n * 256 + t];
    int cnt = hi - lo;
    float pooled = sum / (float)(cnt > 1 ? cnt : 1);
    __shared__ float sp[256];
    __shared__ float sh[128];
    __shared__ float sw[4];
    sp[t] = pooled;
    __syncthreads();
    if (t < 128) {
        float a = bp1[t];
        for (int k = 0; k < 256; k++) a += sp[k] * Wp1[k * 128 + t];
        sh[t] = a > 0.f ? a : 0.f;
    }
    __syncthreads();
    float v = (t < 128) ? sh[t] * Wp2[t] : 0.f;
#pragma unroll
    for (int o = 32; o; o >>= 1) v += __shfl_xor(v, o, 64);
    if ((t & 63) == 0) sw[t >> 6] = v;
    __syncthreads();
    if (t == 0) out[g] = sw[0] + sw[1] + sw[2] + sw[3] + bp2[0];
}

// ---------------- workspace layout (bytes), total ~375 MB
#define XHI_OFF  ((size_t)0)                               // 51.2 MB
#define XLO_OFF  (XHI_OFF + (size_t)N_ * 256 * 2)          // 51.2 MB
#define W0_OFF   ((size_t)0)                               // overlays XHI/XLO
#define XL_OFF   (XLO_OFF + (size_t)N_ * 256 * 2)          // xl fp32 102.4 MB
#define XLB_OFF  (XL_OFF + (size_t)N_ * 256 * 4)           // xl bf16  51.2 MB
#define XRB_OFF  (XLB_OFF + (size_t)N_ * 256 * 2)          // xr bf16  51.2 MB
#define LG_OFF   (XRB_OFF + (size_t)N_ * 256 * 2)          // plog 6.4 MB
#define AL_OFF   (LG_OFF + (size_t)ETOT * 4 * 4)           // alpha_csr 6.4 MB
#define LM_OFF   (AL_OFF + (size_t)ETOT * 4 * 4)           // (unused)
#define DN_OFF   (LM_OFF + (size_t)N_ * 4 * 4)             // (unused)
#define DG_OFF   (DN_OFF + (size_t)N_ * 4 * 4)
#define OF_OFF   (DG_OFF + (size_t)N_ * 4)
#define CU_OFF   (OF_OFF + (size_t)(N_ + 32) * 4)
#define SR_OFF   (CU_OFF + (size_t)N_ * 4)
#define DP_OFF   (SR_OFF + (size_t)ETOT * 4)
#define PE_OFF   (DP_OFF + (size_t)ETOT * 4)
#define RN_OFF   (PE_OFF + (size_t)ETOT * 4)               // rnk [ETOT]
#define SC_OFF   (RN_OFF + (size_t)ETOT * 4)               // srcs_c [E_]
#define DC_OFF   (SC_OFF + (size_t)E_ * 4)                 // dstp_c [E_]
#define PC_OFF   (DC_OFF + (size_t)E_ * 4)                 // posr_c [E_]
#define BS_OFF   (PC_OFF + (size_t)E_ * 4)                 // bsum (scan1)
#define BS2_OFF  (BS_OFF + (size_t)512)                    // bsum2 (scan2) 391*4
#define MS_OFF   (BS2_OFF + (size_t)2048)
#define LE_OFF   (MS_OFF + (size_t)256)
#define WCH_OFF  (LE_OFF + (size_t)2048)
#define WCL_OFF  (WCH_OFF + (size_t)3 * 512 * 256 * 2)
#define WEH_OFF  (WCL_OFF + (size_t)3 * 512 * 256 * 2)
#define EAT_OFF  (WEH_OFF + (size_t)3 * 256 * 64 * 2)      // eattrb rank-ordered 38.4 MB

extern "C" void kernel_launch(void* const* d_in, const int* in_sizes, int n_in,
                              void* d_out, int out_size, void* d_ws, size_t ws_size,
                              hipStream_t stream) {
    const float* x     = (const float*)d_in[0];
    const int*   ei    = (const int*)d_in[1];
    const float* eattr = (const float*)d_in[2];
    const int*   batch = (const int*)d_in[3];
    const float* Wl    = (const float*)d_in[4];
    const float* bl    = (const float*)d_in[5];
    const float* Wr    = (const float*)d_in[6];
    const float* br    = (const float*)d_in[7];
    const float* We    = (const float*)d_in[8];
    const float* att   = (const float*)d_in[9];
    const float* bias  = (const float*)d_in[10];
    const float* Wp1   = (const float*)d_in[11];
    const float* bp1   = (const float*)d_in[12];
    const float* Wp2   = (const float*)d_in[13];
    const float* bp2   = (const float*)d_in[14];

    char* ws = (char*)d_ws;
    short*    xhi     = (short*)(ws + XHI_OFF);
    short*    xlo     = (short*)(ws + XLO_OFF);
    float*    w0      = (float*)(ws + W0_OFF);
    float*    xl      = (float*)(ws + XL_OFF);
    short*    xlb     = (short*)(ws + XLB_OFF);
    short*    xrb     = (short*)(ws + XRB_OFF);
    float*    plog    = (float*)(ws + LG_OFF);
    float*    alpha   = (float*)(ws + AL_OFF);
    int*      deg     = (int*)(ws + DG_OFF);
    int*      off     = (int*)(ws + OF_OFF);
    int*      cursor  = (int*)(ws + CU_OFF);
    int*      srcs    = (int*)(ws + SR_OFF);
    int*      dstp    = (int*)(ws + DP_OFF);
    int*      pose    = (int*)(ws + PE_OFF);
    int*      rnk     = (int*)(ws + RN_OFF);
    int*      srcs_c  = (int*)(ws + SC_OFF);
    int*      dstp_c  = (int*)(ws + DC_OFF);
    int*      posr_c  = (int*)(ws + PC_OFF);
    int*      bsum    = (int*)(ws + BS_OFF);
    int*      bsum2   = (int*)(ws + BS2_OFF);
    float*    meansum = (float*)(ws + MS_OFF);
    float*    loope   = (float*)(ws + LE_OFF);
    short*    wcatH   = (short*)(ws + WCH_OFF);
    short*    wcatL   = (short*)(ws + WCL_OFF);
    short*    weH     = (short*)(ws + WEH_OFF);
    short*    eattrb  = (short*)(ws + EAT_OFF);

    // setup
    hipMemsetAsync(meansum, 0, 64 * 4, stream);
    hipMemsetAsync(deg, 0, (size_t)N_ * 4, stream);
    mean_kernel<<<512, 256, 0, stream>>>(eattr, meansum);
    prep_wcat_kernel<<<(3 * 512 * 256 + 255) / 256, 256, 0, stream>>>(Wl, Wr, wcatH, wcatL);
    prep_we_kernel<<<(3 * 256 * 64 + 255) / 256, 256, 0, stream>>>(We, weH);
    split_x_kernel<<<(N_ * 32 + 255) / 256, 256, 0, stream>>>(x, xhi, xlo);
    hist_kernel<<<(ETOT + 255) / 256, 256, 0, stream>>>(ei, deg);
    scanA_kernel<<<NB_SCAN, 256, 0, stream>>>(deg, off, bsum);
    scanB_kernel<<<1, 64, 0, stream>>>(bsum, NB_SCAN);
    scanC_kernel<<<(N_ + 255) / 256, 256, 0, stream>>>(off, bsum);
    hipMemcpyAsync(cursor, off, (size_t)N_ * 4, hipMemcpyDeviceToDevice, stream);
    scatter_kernel<<<(ETOT + 255) / 256, 256, 0, stream>>>(ei, cursor, srcs, dstp, pose);
    // rank-compaction of real edges (CSR order, gaps removed)
    scanA2_kernel<<<NB_SCAN2, 256, 0, stream>>>(srcs, dstp, rnk, bsum2);
    scanB_kernel<<<1, 64, 0, stream>>>(bsum2, NB_SCAN2);
    scanC2_kernel<<<(ETOT + 255) / 256, 256, 0, stream>>>(rnk, bsum2);
    compact_kernel<<<(ETOT + 255) / 256, 256, 0, stream>>>(srcs, dstp, rnk, srcs_c, dstp_c, posr_c);
    split_e_kernel<<<(E_ * 8 + 255) / 256, 256, 0, stream>>>(eattr, eattrb, pose, rnk);

    const int mtN = (N_ + BM - 1) / BM;         // 782
    const int nwgN = 4 * mtN;                   // 3128
    const int mtE = (E_ + 127) / 128;           // 2344
    const int nwgE = 2 * mtE;                   // 4688

    for (int l = 0; l < 3; l++) {
        const float* We_l = We + (size_t)l * 64 * 256;
        const float* att_l = att + (size_t)l * 256;
        loope_kernel<<<1, 256, 0, stream>>>(meansum, We_l, loope);
        // xl (fp32+bf16) | xr (bf16 only), fp32-split 3-pass path
        mfma_gemm_node<<<nwgN, 256, 0, stream>>>(
            xhi, xlo, wcatH + (size_t)l * 512 * 256, wcatL + (size_t)l * 512 * 256,
            xl, xlb, xrb, bl + (size_t)l * 256, br + (size_t)l * 256, N_, 256);
        edge_fused_kernel<<<nwgE, 256, 0, stream>>>(
            eattrb, weH + (size_t)l * 256 * 64, srcs_c, dstp_c, posr_c, xlb, xrb, att_l, plog);
        self_logits_kernel<<<(N_ + 3) / 4, 256, 0, stream>>>(xlb, xrb, loope, att_l, pose, plog);
        softmax_node_kernel<<<(N_ + 3) / 4, 256, 0, stream>>>(off, plog, alpha);
        // layers 0,1: write next layer's hi/lo splits (no fp32); layer 2: fp32 for pool
        agg_kernel<<<(N_ + 3) / 4, 256, 0, stream>>>(
            xl, alpha, off, srcs, bias + (size_t)l * 256,
            (l == 2) ? w0 : nullptr,
            (l < 2) ? xhi : nullptr,
            (l < 2) ? xlo : nullptr);
    }

    pool_mlp_kernel<<<G_, 256, 0, stream>>>(w0, batch, Wp1, bp1, Wp2, bp2, (float*)d_out);
}

// Round 6
// 1463.028 us; speedup vs baseline: 1.4074x; 1.1139x over previous
//
#include <hip/hip_runtime.h>
#include <hip/hip_bf16.h>

#define N_ 100000
#define E_ 300000
#define ETOT 400000
#define G_ 2048
#define NB_SCAN 98        // ceil(N_/1024)
#define NB_SCAN2 391      // ceil(ETOT/1024)

typedef __attribute__((ext_vector_type(8))) short bf16x8;
typedef __attribute__((ext_vector_type(4))) float f32x4;

__device__ __forceinline__ short f2bf(float f) {
    __hip_bfloat16 h = __float2bfloat16(f);
    return *reinterpret_cast<short*>(&h);
}
__device__ __forceinline__ float bf2f(short s) {
    __hip_bfloat16 h = *reinterpret_cast<__hip_bfloat16*>(&s);
    return __bfloat162float(h);
}

// async global->LDS, 16B per lane. LDS dest is wave-uniform base + lane*16.
typedef __attribute__((address_space(1))) void* gas_ptr;
typedef __attribute__((address_space(3))) void* las_ptr;
__device__ __forceinline__ void gload16(const void* g, void* l) {
    __builtin_amdgcn_global_load_lds((gas_ptr)g, (las_ptr)l, 16, 0, 0);
}

// bijective XCD swizzle (m204)
__device__ __forceinline__ int xcd_swz(int bid, int nwg) {
    int q = nwg >> 3, rr = nwg & 7;
    int xcd = bid & 7, i = bid >> 3;
    return (xcd < rr) ? xcd * (q + 1) + i : rr * (q + 1) + (xcd - rr) * q + i;
}

// ---------------- mean of edge_attr over rows -> meansum[64] (sum; divide later)
__global__ __launch_bounds__(256) void mean_kernel(const float* __restrict__ ea, float* __restrict__ meansum) {
    __shared__ float s[256];
    int tid = threadIdx.x;
    int col = tid & 63, rg = tid >> 6;
    float acc = 0.f;
    for (long long row = (long long)blockIdx.x * 4 + rg; row < E_; row += (long long)gridDim.x * 4)
        acc += ea[row * 64 + col];
    s[tid] = acc;
    __syncthreads();
    if (tid < 64) atomicAdd(meansum + tid, s[tid] + s[tid + 64] + s[tid + 128] + s[tid + 192]);
}

// ---------------- loop_e[c] = (meansum/E) @ We_l
__global__ __launch_bounds__(256) void loope_kernel(const float* __restrict__ meansum,
                                                    const float* __restrict__ We_l,
                                                    float* __restrict__ loope) {
    int c = threadIdx.x;
    float acc = 0.f;
    const float invE = 1.0f / (float)E_;
    for (int k = 0; k < 64; k++) acc += (meansum[k] * invE) * We_l[k * 256 + c];
    loope[c] = acc;
}

// swizzled column within 32-col window: chunk c -> c ^ ((row>>1)&3)
__device__ __forceinline__ int swz_col(int row, int k) {
    int c = (k >> 3) & 3;
    int s = (row >> 1) & 3;
    return (k & ~31) | ((c ^ s) << 3) | (k & 7);
}

// ---------------- weight prep: split fp32 -> (hi,lo) bf16, transposed to [n][k], pre-swizzled
__global__ __launch_bounds__(256) void prep_wcat_kernel(const float* __restrict__ Wl, const float* __restrict__ Wr,
                                                        short* __restrict__ hi, short* __restrict__ lo) {
    int idx = blockIdx.x * 256 + threadIdx.x;
    if (idx >= 3 * 512 * 256) return;
    int l = idx / (512 * 256);
    int rem = idx % (512 * 256);
    int n = rem >> 8, k = rem & 255;
    float v = (n < 256) ? Wl[((size_t)l * 256 + k) * 256 + n]
                        : Wr[((size_t)l * 256 + k) * 256 + (n - 256)];
    short h = f2bf(v);
    size_t o = (size_t)l * 512 * 256 + (size_t)n * 256 + swz_col(n, k);
    hi[o] = h;
    lo[o] = f2bf(v - bf2f(h));
}

__global__ __launch_bounds__(256) void prep_we_kernel(const float* __restrict__ We,
                                                      short* __restrict__ hi) {
    int idx = blockIdx.x * 256 + threadIdx.x;
    if (idx >= 3 * 256 * 64) return;
    int l = idx / (256 * 64);
    int rem = idx % (256 * 64);
    int n = rem >> 6, k = rem & 63;
    float v = We[((size_t)l * 64 + k) * 256 + n];
    hi[(size_t)l * 256 * 64 + (size_t)n * 64 + swz_col(n, k)] = f2bf(v);
}

// ---------------- split x fp32 [N_][256] -> pre-swizzled bf16 hi/lo
__global__ __launch_bounds__(256) void split_x_kernel(const float* __restrict__ in,
                                                      short* __restrict__ hi, short* __restrict__ lo) {
    int idx = blockIdx.x * 256 + threadIdx.x;
    if (idx >= N_ * 32) return;
    int gm = idx >> 5, cw = idx & 31;
    int c = cw & 3, win = cw >> 2;
    int s = (gm >> 1) & 3;
    const float* src = in + (size_t)gm * 256 + (win << 5) + (c << 3);
    float4 f0 = *(const float4*)src;
    float4 f1 = *(const float4*)(src + 4);
    float f[8] = {f0.x, f0.y, f0.z, f0.w, f1.x, f1.y, f1.z, f1.w};
    bf16x8 vh, vl;
#pragma unroll
    for (int j = 0; j < 8; j++) {
        short h = f2bf(f[j]);
        vh[j] = h;
        vl[j] = f2bf(f[j] - bf2f(h));
    }
    size_t o = (size_t)gm * 256 + (win << 5) + ((c ^ s) << 3);
    *(bf16x8*)(hi + o) = vh;
    *(bf16x8*)(lo + o) = vl;
}

// ---------------- eattr fp32 [E_][64] -> bf16, permuted to RANK (compacted CSR) order, pre-swizzled
__global__ __launch_bounds__(256) void split_e_kernel(const float* __restrict__ in, short* __restrict__ hi,
                                                      const int* __restrict__ pose, const int* __restrict__ rnk) {
    int idx = blockIdx.x * 256 + threadIdx.x;
    if (idx >= E_ * 8) return;
    int e = idx >> 3, cw = idx & 7;
    int c = cw & 3, win = cw >> 2;
    int rk = rnk[pose[e]];
    int s = (rk >> 1) & 3;
    const float* src = in + (size_t)e * 64 + (win << 5) + (c << 3);
    float4 f0 = *(const float4*)src;
    float4 f1 = *(const float4*)(src + 4);
    float f[8] = {f0.x, f0.y, f0.z, f0.w, f1.x, f1.y, f1.z, f1.w};
    bf16x8 vh;
#pragma unroll
    for (int j = 0; j < 8; j++) vh[j] = f2bf(f[j]);
    *(bf16x8*)(hi + (size_t)rk * 64 + (win << 5) + ((c ^ s) << 3)) = vh;
}

// ---------------- CSR build over dst (self loops e>=E_ have dst = e-E_)
__global__ __launch_bounds__(256) void hist_kernel(const int* __restrict__ ei, int* __restrict__ deg) {
    int e = blockIdx.x * 256 + threadIdx.x;
    if (e >= ETOT) return;
    int d = (e < E_) ? ei[E_ + e] : (e - E_);
    atomicAdd(deg + d, 1);
}

__global__ __launch_bounds__(256) void scanA_kernel(const int* __restrict__ deg, int* __restrict__ off,
                                                    int* __restrict__ bsum) {
    __shared__ int s[256];
    int tid = threadIdx.x;
    int base = blockIdx.x * 1024 + tid * 4;
    int v[4];
#pragma unroll
    for (int i = 0; i < 4; i++) v[i] = (base + i < N_) ? deg[base + i] : 0;
    v[1] += v[0]; v[2] += v[1]; v[3] += v[2];
    s[tid] = v[3];
    __syncthreads();
    for (int o = 1; o < 256; o <<= 1) {
        int t = (tid >= o) ? s[tid - o] : 0;
        __syncthreads();
        s[tid] += t;
        __syncthreads();
    }
    int prev = tid ? s[tid - 1] : 0;
#pragma unroll
    for (int i = 0; i < 4; i++)
        if (base + i < N_) off[base + i + 1] = prev + v[i];
    if (tid == 255) bsum[blockIdx.x] = s[255];
}

__global__ void scanB_kernel(int* __restrict__ bsum, int n) {
    if (threadIdx.x == 0) {
        int run = 0;
        for (int i = 0; i < n; i++) { int t = bsum[i]; bsum[i] = run; run += t; }
    }
}

__global__ __launch_bounds__(256) void scanC_kernel(int* __restrict__ off, const int* __restrict__ bsum) {
    int i = blockIdx.x * 256 + threadIdx.x;
    if (i < N_) {
        off[i + 1] += bsum[i >> 10];
        if (i == 0) off[0] = 0;
    }
}

// scatter: srcs[pos]=src; dstp[pos]=dst; pose[e]=pos
__global__ __launch_bounds__(256) void scatter_kernel(const int* __restrict__ ei, int* __restrict__ cursor,
                                                      int* __restrict__ srcs, int* __restrict__ dstp,
                                                      int* __restrict__ pose) {
    int e = blockIdx.x * 256 + threadIdx.x;
    if (e >= ETOT) return;
    int s, d;
    if (e < E_) { s = ei[e]; d = ei[E_ + e]; }
    else        { s = e - E_; d = s; }
    int pos = atomicAdd(cursor + d, 1);
    srcs[pos] = s;
    dstp[pos] = d;
    pose[e] = pos;
}

// ---------------- rank scan: rnk[pos] = exclusive prefix of (srcs[pos]!=dstp[pos]) over ETOT
__global__ __launch_bounds__(256) void scanA2_kernel(const int* __restrict__ srcs, const int* __restrict__ dstp,
                                                     int* __restrict__ rnk, int* __restrict__ bsum2) {
    __shared__ int sm[256];
    int tid = threadIdx.x;
    int base = blockIdx.x * 1024 + tid * 4;
    int v[4];
#pragma unroll
    for (int i = 0; i < 4; i++) {
        int p = base + i;
        v[i] = (p < ETOT && srcs[p] != dstp[p]) ? 1 : 0;
    }
    int incl1 = v[0] + v[1], incl2 = incl1 + v[2], incl3 = incl2 + v[3];
    sm[tid] = incl3;
    __syncthreads();
    for (int o = 1; o < 256; o <<= 1) {
        int t = (tid >= o) ? sm[tid - o] : 0;
        __syncthreads();
        sm[tid] += t;
        __syncthreads();
    }
    int prev = tid ? sm[tid - 1] : 0;
    int incl[4] = {v[0], incl1, incl2, incl3};
#pragma unroll
    for (int i = 0; i < 4; i++) {
        int p = base + i;
        if (p < ETOT) rnk[p] = prev + incl[i] - v[i];
    }
    if (tid == 255) bsum2[blockIdx.x] = sm[255];
}

__global__ __launch_bounds__(256) void scanC2_kernel(int* __restrict__ rnk, const int* __restrict__ bsum2) {
    int p = blockIdx.x * 256 + threadIdx.x;
    if (p < ETOT) rnk[p] += bsum2[p >> 10];
}

// compacted per-rank arrays (real edges only, CSR order)
__global__ __launch_bounds__(256) void compact_kernel(const int* __restrict__ srcs, const int* __restrict__ dstp,
                                                      const int* __restrict__ rnk,
                                                      int* __restrict__ srcs_c, int* __restrict__ dstp_c,
                                                      int* __restrict__ posr_c) {
    int pos = blockIdx.x * 256 + threadIdx.x;
    if (pos >= ETOT) return;
    int s = srcs[pos], d = dstp[pos];
    if (s != d) {
        int rk = rnk[pos];
        srcs_c[rk] = s;
        dstp_c[rk] = d;
        posr_c[rk] = pos;
    }
}

// ---------------- node GEMM: split-bf16 3-pass MFMA (fp32-accurate), m97 structure.
// Output (n0<256): xsp[N][512] shorts — per row, 64 groups of 4 cols: [hi x4 | lo x4].
// Serves edge/self logits (hi short4, bit-identical to old xlb) and agg (short8 ->
// reconstruct hi+lo ~ fp32 to 2^-17 rel). n0>=256: xrb bf16 as before.
#define BM 128

__global__ __launch_bounds__(256, 4) void mfma_gemm_node(
    const short* __restrict__ Ahi_g, const short* __restrict__ Alo_g,
    const short* __restrict__ Bhi_g, const short* __restrict__ Blo_g,
    short* __restrict__ Csp, short* __restrict__ C1b,
    const float* __restrict__ bias0, const float* __restrict__ bias1,
    int M, int K) {
    __shared__ short Ah[BM * 32];
    __shared__ short Bh[BM * 32];
    __shared__ short Al[BM * 32];
    __shared__ short Bl[BM * 32];

    const int v = xcd_swz(blockIdx.x, gridDim.x);
    const int n0 = (v & 3) * BM;
    const int m0 = (v >> 2) * BM;
    const int tid = threadIdx.x;
    const int wave = tid >> 6, lane = tid & 63;
    const int wm = (wave >> 1) << 6, wn = (wave & 1) << 6;
    const int r = lane & 15, q = lane >> 4;
    const int qs = (q ^ ((r >> 1) & 3)) << 3;   // physical chunk (shorts)

    const int srow = (wave << 5) + (lane >> 2);
    const int sch = (lane & 3) << 3;
    int ga0 = m0 + srow;       if (ga0 > M - 1) ga0 = M - 1;
    int ga1 = m0 + srow + 16;  if (ga1 > M - 1) ga1 = M - 1;
    const int offA0 = ga0 * K + sch;
    const int offA1 = ga1 * K + sch;
    const int offB0 = (n0 + srow) * K + sch;
    const int offB1 = (n0 + srow + 16) * K + sch;
    short* lA0 = &Ah[(wave << 5) * 32];
    short* lA1 = lA0 + 16 * 32;
    short* lB0 = &Bh[(wave << 5) * 32];
    short* lB1 = lB0 + 16 * 32;
    short* lAl0 = &Al[(wave << 5) * 32];
    short* lAl1 = lAl0 + 16 * 32;
    short* lBl0 = &Bl[(wave << 5) * 32];
    short* lBl1 = lBl0 + 16 * 32;

    f32x4 acc[4][4];
#pragma unroll
    for (int i = 0; i < 4; i++)
#pragma unroll
        for (int j = 0; j < 4; j++) acc[i][j] = (f32x4){0.f, 0.f, 0.f, 0.f};

    for (int k0 = 0; k0 < K; k0 += 32) {
        gload16(Ahi_g + offA0 + k0, lA0);
        gload16(Ahi_g + offA1 + k0, lA1);
        gload16(Bhi_g + offB0 + k0, lB0);
        gload16(Bhi_g + offB1 + k0, lB1);
        gload16(Alo_g + offA0 + k0, lAl0);
        gload16(Alo_g + offA1 + k0, lAl1);
        gload16(Blo_g + offB0 + k0, lBl0);
        gload16(Blo_g + offB1 + k0, lBl1);
        __syncthreads();   // compiler drains vmcnt before s_barrier

        bf16x8 ah[4], bh[4];
#pragma unroll
        for (int f = 0; f < 4; f++) {
            ah[f] = *(const bf16x8*)(Ah + (wm + f * 16 + r) * 32 + qs);
            bh[f] = *(const bf16x8*)(Bh + (wn + f * 16 + r) * 32 + qs);
        }
#pragma unroll
        for (int fm = 0; fm < 4; fm++)
#pragma unroll
            for (int fn = 0; fn < 4; fn++)
                acc[fm][fn] = __builtin_amdgcn_mfma_f32_16x16x32_bf16(ah[fm], bh[fn], acc[fm][fn], 0, 0, 0);
        bf16x8 t[4];
#pragma unroll
        for (int f = 0; f < 4; f++) t[f] = *(const bf16x8*)(Bl + (wn + f * 16 + r) * 32 + qs);
#pragma unroll
        for (int fm = 0; fm < 4; fm++)
#pragma unroll
            for (int fn = 0; fn < 4; fn++)
                acc[fm][fn] = __builtin_amdgcn_mfma_f32_16x16x32_bf16(ah[fm], t[fn], acc[fm][fn], 0, 0, 0);
#pragma unroll
        for (int f = 0; f < 4; f++) t[f] = *(const bf16x8*)(Al + (wm + f * 16 + r) * 32 + qs);
#pragma unroll
        for (int fm = 0; fm < 4; fm++)
#pragma unroll
            for (int fn = 0; fn < 4; fn++)
                acc[fm][fn] = __builtin_amdgcn_mfma_f32_16x16x32_bf16(t[fm], bh[fn], acc[fm][fn], 0, 0, 0);
        __syncthreads();
    }

    // epilogue: C/D map col=lane&15, row=q*4+reg
    const bool second = (n0 >= 256);
    const int ncol = second ? n0 - 256 : n0;
    const float* bs = second ? bias1 : bias0;
#pragma unroll
    for (int fm = 0; fm < 4; fm++) {
#pragma unroll
        for (int fn = 0; fn < 4; fn++) {
            int col = ncol + wn + fn * 16 + r;
            float bv = bs[col];
#pragma unroll
            for (int g = 0; g < 4; g++) {
                int row = m0 + wm + fm * 16 + q * 4 + g;
                if (row < M) {
                    float vv = acc[fm][fn][g] + bv;
                    if (second) {
                        C1b[(size_t)row * 256 + col] = f2bf(vv);
                    } else {
                        short hh = f2bf(vv);
                        short ll = f2bf(vv - bf2f(hh));
                        size_t o2 = (size_t)row * 512 + ((size_t)(col >> 2) << 3) + (col & 3);
                        Csp[o2] = hh;
                        Csp[o2 + 4] = ll;
                    }
                }
            }
        }
    }
}

// ---------------- FUSED edge GEMM (eattr_bf16 @ We) + leaky_relu + att-dot.
// Rank-compacted CSR order (real edges only). C tile staged bf16 in LDS (coalesced
// short4 gathers in the reduce), GEMM staging buffers UNIONED into the same LDS.
// No atomics: plog writes only; segment softmax fused into agg_kernel.
__global__ __launch_bounds__(256, 4) void edge_fused_kernel(
    const short* __restrict__ Ag,       // eattrb [E_][64] rank-ordered pre-swizzled
    const short* __restrict__ Bg,       // We layer [256][64] pre-swizzled
    const int* __restrict__ srcs_c, const int* __restrict__ dstp_c, const int* __restrict__ posr_c,
    const short* __restrict__ xsp, const short* __restrict__ xrb,
    const float* __restrict__ att,      // layer att [256]
    float* __restrict__ plog) {
    __shared__ short smem[128 * 132];   // union: {Ah,Bh} then Ct
    short* Ah = smem;                   // [128*32]
    short* Bh = smem + 128 * 32;        // [128*32]
    short* Ct = smem;                   // [128*132] after barrier

    const int v = xcd_swz(blockIdx.x, gridDim.x);
    const int n0 = (v & 1) << 7;
    const int m0 = (v >> 1) << 7;
    const int tid = threadIdx.x;
    const int wave = tid >> 6, lane = tid & 63;
    const int wm = (wave >> 1) << 6, wn = (wave & 1) << 6;
    const int r = lane & 15, q = lane >> 4;
    const int qs = (q ^ ((r >> 1) & 3)) << 3;

    const int srow = (wave << 5) + (lane >> 2);
    const int sch = (lane & 3) << 3;
    int ga0 = m0 + srow;       if (ga0 > E_ - 1) ga0 = E_ - 1;
    int ga1 = m0 + srow + 16;  if (ga1 > E_ - 1) ga1 = E_ - 1;
    const int offA0 = ga0 * 64 + sch;
    const int offA1 = ga1 * 64 + sch;
    const int offB0 = (n0 + srow) * 64 + sch;
    const int offB1 = (n0 + srow + 16) * 64 + sch;
    short* lA0 = Ah + (wave << 5) * 32;
    short* lA1 = lA0 + 16 * 32;
    short* lB0 = Bh + (wave << 5) * 32;
    short* lB1 = lB0 + 16 * 32;

    f32x4 acc[4][4];
#pragma unroll
    for (int i = 0; i < 4; i++)
#pragma unroll
        for (int j = 0; j < 4; j++) acc[i][j] = (f32x4){0.f, 0.f, 0.f, 0.f};

#pragma unroll
    for (int k0 = 0; k0 < 64; k0 += 32) {
        gload16(Ag + offA0 + k0, lA0);
        gload16(Ag + offA1 + k0, lA1);
        gload16(Bg + offB0 + k0, lB0);
        gload16(Bg + offB1 + k0, lB1);
        __syncthreads();
        bf16x8 ah[4], bh[4];
#pragma unroll
        for (int f = 0; f < 4; f++) {
            ah[f] = *(const bf16x8*)(Ah + (wm + f * 16 + r) * 32 + qs);
            bh[f] = *(const bf16x8*)(Bh + (wn + f * 16 + r) * 32 + qs);
        }
#pragma unroll
        for (int fm = 0; fm < 4; fm++)
#pragma unroll
            for (int fn = 0; fn < 4; fn++)
                acc[fm][fn] = __builtin_amdgcn_mfma_f32_16x16x32_bf16(ah[fm], bh[fn], acc[fm][fn], 0, 0, 0);
        __syncthreads();
    }

    // write C tile to LDS as bf16 (Ah/Bh dead past the barrier above)
#pragma unroll
    for (int fm = 0; fm < 4; fm++)
#pragma unroll
        for (int fn = 0; fn < 4; fn++)
#pragma unroll
            for (int g = 0; g < 4; g++)
                Ct[(wm + fm * 16 + q * 4 + g) * 132 + wn + fn * 16 + r] = f2bf(acc[fm][fn][g]);
    __syncthreads();

    // reduction: wave handles ranks [wave*32, wave*32+32), 2 per iter; short4 gathers
    const int half = lane >> 5;             // rank parity within pair
    const int hsel = (lane >> 4) & 1;       // head within the 128-col tile
    const int sub = lane & 15;
    const int colL = (hsel << 6) + (sub << 2);
    const float4 w = *(const float4*)(att + n0 + colL);
    const int hglob = (n0 >> 6) + hsel;
    const int gc2 = (n0 + colL) << 1;       // xsp short offset of hi group
    for (int it = 0; it < 16; it++) {
        int prow = (wave << 5) + (it << 1) + half;
        int ec = m0 + prow;
        bool valid = (ec < E_);
        int s = 0, d = 0, pos = 0;
        if (valid) { s = srcs_c[ec]; d = dstp_c[ec]; pos = posr_c[ec]; }
        short4 ev = *(const short4*)(Ct + prow * 132 + colL);
        short4 a = valid ? *(const short4*)(xsp + (size_t)s * 512 + gc2) : make_short4(0, 0, 0, 0);
        short4 b = valid ? *(const short4*)(xrb + (size_t)d * 256 + n0 + colL) : make_short4(0, 0, 0, 0);
        float m0v = bf2f(a.x) + bf2f(b.x) + bf2f(ev.x);
        float m1v = bf2f(a.y) + bf2f(b.y) + bf2f(ev.y);
        float m2v = bf2f(a.z) + bf2f(b.z) + bf2f(ev.z);
        float m3v = bf2f(a.w) + bf2f(b.w) + bf2f(ev.w);
        m0v = (m0v > 0.f) ? m0v : 0.2f * m0v;
        m1v = (m1v > 0.f) ? m1v : 0.2f * m1v;
        m2v = (m2v > 0.f) ? m2v : 0.2f * m2v;
        m3v = (m3v > 0.f) ? m3v : 0.2f * m3v;
        float rr = m0v * w.x + m1v * w.y + m2v * w.z + m3v * w.w;
#pragma unroll
        for (int o = 1; o < 16; o <<= 1) rr += __shfl_xor(rr, o, 64);
        if (valid && sub == 0)
            plog[(size_t)pos * 4 + hglob] = rr;
    }
}

// ---------------- self-loop logits (src=dst=n, erow=loope fp32); writes plog[pose[E_+n]]
__global__ __launch_bounds__(256) void self_logits_kernel(const short* __restrict__ xsp, const short* __restrict__ xrb,
                                                          const float* __restrict__ loope, const float* __restrict__ att,
                                                          const int* __restrict__ pose,
                                                          float* __restrict__ plog) {
    int wid = threadIdx.x >> 6;
    int lane = threadIdx.x & 63;
    int n = blockIdx.x * 4 + wid;
    if (n >= N_) return;
    short4 a = *(const short4*)(xsp + (size_t)n * 512 + (lane << 3));   // hi group
    short4 b = *(const short4*)(xrb + (size_t)n * 256 + lane * 4);
    float4 c = *(const float4*)(loope + lane * 4);
    float4 w = *(const float4*)(att + lane * 4);
    float m0 = bf2f(a.x) + bf2f(b.x) + c.x;
    float m1 = bf2f(a.y) + bf2f(b.y) + c.y;
    float m2 = bf2f(a.z) + bf2f(b.z) + c.z;
    float m3 = bf2f(a.w) + bf2f(b.w) + c.w;
    m0 = (m0 > 0.f) ? m0 : 0.2f * m0;
    m1 = (m1 > 0.f) ? m1 : 0.2f * m1;
    m2 = (m2 > 0.f) ? m2 : 0.2f * m2;
    m3 = (m3 > 0.f) ? m3 : 0.2f * m3;
    float r = m0 * w.x + m1 * w.y + m2 * w.z + m3 * w.w;
#pragma unroll
    for (int o = 1; o < 16; o <<= 1) r += __shfl_xor(r, o, 64);
    int pos = pose[E_ + n];
    if ((lane & 15) == 0)
        plog[(size_t)pos * 4 + (lane >> 4)] = r;
}

// ---------------- FUSED per-node softmax + CSR aggregation, wave-per-node.
// Softmax math identical to prior softmax_node (same strided-16 tree reduce, same
// /(sum+1e-16)); agg accumulation order identical; xl[src] = bf2f(hi)+bf2f(lo).
__global__ __launch_bounds__(256) void agg_kernel(const short* __restrict__ xsp, const float* __restrict__ plog,
                                                  const int* __restrict__ off, const int* __restrict__ srcs,
                                                  const float* __restrict__ bias,
                                                  float* __restrict__ xf32, short* __restrict__ xhi,
                                                  short* __restrict__ xlo) {
    int wid = threadIdx.x >> 6, lane = threadIdx.x & 63;
    int d = blockIdx.x * 4 + wid;
    if (d >= N_) return;
    int s0 = off[d], s1 = off[d + 1];
    int sub = lane & 15, h = lane >> 4;
    // segment softmax stats (coalesced: 64 lanes cover 16 rows x 4 heads = 256B)
    float mx = -3.4e38f;
    for (int i = s0 + sub; i < s1; i += 16)
        mx = fmaxf(mx, plog[(size_t)i * 4 + h]);
#pragma unroll
    for (int o = 1; o < 16; o <<= 1) mx = fmaxf(mx, __shfl_xor(mx, o, 64));
    float sum = 0.f;
    for (int i = s0 + sub; i < s1; i += 16)
        sum += expf(plog[(size_t)i * 4 + h] - mx);
#pragma unroll
    for (int o = 1; o < 16; o <<= 1) sum += __shfl_xor(sum, o, 64);
    float dn = sum + 1e-16f;

    float4 acc = make_float4(0.f, 0.f, 0.f, 0.f);
    int i = s0;
    for (; i + 2 <= s1; i += 2) {
        int a0 = srcs[i], a1 = srcs[i + 1];
        float w0 = expf(plog[(size_t)i * 4 + h] - mx) / dn;
        float w1 = expf(plog[(size_t)(i + 1) * 4 + h] - mx) / dn;
        bf16x8 v0 = *(const bf16x8*)(xsp + (size_t)a0 * 512 + (lane << 3));
        bf16x8 v1 = *(const bf16x8*)(xsp + (size_t)a1 * 512 + (lane << 3));
        float x00 = bf2f(v0[0]) + bf2f(v0[4]);
        float x01 = bf2f(v0[1]) + bf2f(v0[5]);
        float x02 = bf2f(v0[2]) + bf2f(v0[6]);
        float x03 = bf2f(v0[3]) + bf2f(v0[7]);
        float x10 = bf2f(v1[0]) + bf2f(v1[4]);
        float x11 = bf2f(v1[1]) + bf2f(v1[5]);
        float x12 = bf2f(v1[2]) + bf2f(v1[6]);
        float x13 = bf2f(v1[3]) + bf2f(v1[7]);
        acc.x += w0 * x00 + w1 * x10;
        acc.y += w0 * x01 + w1 * x11;
        acc.z += w0 * x02 + w1 * x12;
        acc.w += w0 * x03 + w1 * x13;
    }
    if (i < s1) {
        int a0 = srcs[i];
        float w0 = expf(plog[(size_t)i * 4 + h] - mx) / dn;
        bf16x8 v0 = *(const bf16x8*)(xsp + (size_t)a0 * 512 + (lane << 3));
        acc.x += w0 * (bf2f(v0[0]) + bf2f(v0[4]));
        acc.y += w0 * (bf2f(v0[1]) + bf2f(v0[5]));
        acc.z += w0 * (bf2f(v0[2]) + bf2f(v0[6]));
        acc.w += w0 * (bf2f(v0[3]) + bf2f(v0[7]));
    }
    int col = lane << 2;
    float4 bv = *(const float4*)(bias + col);
    float4 v;
    v.x = acc.x + bv.x; v.x = v.x > 0.f ? v.x : 0.f;
    v.y = acc.y + bv.y; v.y = v.y > 0.f ? v.y : 0.f;
    v.z = acc.z + bv.z; v.z = v.z > 0.f ? v.z : 0.f;
    v.w = acc.w + bv.w; v.w = v.w > 0.f ? v.w : 0.f;
    if (xf32) *(float4*)(xf32 + (size_t)d * 256 + col) = v;
    if (xhi) {
        int c = (lane >> 1) & 3, s = (d >> 1) & 3;
        size_t o = (size_t)d * 256 + (col & ~31) + ((c ^ s) << 3) + (col & 7);
        float f[4] = {v.x, v.y, v.z, v.w};
        short4 hh, ll;
        short* ph = (short*)&hh;
        short* pl = (short*)&ll;
#pragma unroll
        for (int j = 0; j < 4; j++) {
            ph[j] = f2bf(f[j]);
            pl[j] = f2bf(f[j] - bf2f(ph[j]));
        }
        *(short4*)(xhi + o) = hh;
        *(short4*)(xlo + o) = ll;
    }
}

// ---------------- per-graph mean pool + 2-layer MLP head
__device__ __forceinline__ int lbound(const int* __restrict__ a, int n, int v) {
    int lo = 0, hi = n;
    while (lo < hi) { int mid = (lo + hi) >> 1; if (a[mid] < v) lo = mid + 1; else hi = mid; }
    return lo;
}

__global__ __launch_bounds__(256) void pool_mlp_kernel(const float* __restrict__ x, const int* __restrict__ batch,
                                                       const float* __restrict__ Wp1, const float* __restrict__ bp1,
                                                       const float* __restrict__ Wp2, const float* __restrict__ bp2,
                                                       float* __restrict__ out) {
    int g = blockIdx.x;
    int t = threadIdx.x;
    int lo = lbound(batch, N_, g);
    int hi = lbound(batch, N_, g + 1);
    float sum = 0.f;
    for (int n = lo; n < hi; n++) sum += x[(size_t)n * 256 + t];
    int cnt = hi - lo;
    float pooled = sum / (float)(cnt > 1 ? cnt : 1);
    __shared__ float sp[256];
    __shared__ float sh[128];
    __shared__ float sw[4];
    sp[t] = pooled;
    __syncthreads();
    if (t < 128) {
        float a = bp1[t];
        for (int k = 0; k < 256; k++) a += sp[k] * Wp1[k * 128 + t];
        sh[t] = a > 0.f ? a : 0.f;
    }
    __syncthreads();
    float v = (t < 128) ? sh[t] * Wp2[t] : 0.f;
#pragma unroll
    for (int o = 32; o; o >>= 1) v += __shfl_xor(v, o, 64);
    if ((t & 63) == 0) sw[t >> 6] = v;
    __syncthreads();
    if (t == 0) out[g] = sw[0] + sw[1] + sw[2] + sw[3] + bp2[0];
}

// ---------------- workspace layout (bytes), total ~320 MB
// xhi/xlo (GEMM A-input splits) overlay the w0 region: w0 fp32 written only by
// layer-2 agg (after the last GEMM read of xhi/xlo) and read by pool_mlp.
#define XHI_OFF  ((size_t)0)                               // 51.2 MB
#define XLO_OFF  (XHI_OFF + (size_t)N_ * 256 * 2)          // 51.2 MB
#define W0_OFF   ((size_t)0)                               // overlays XHI/XLO
#define XSP_OFF  (XLO_OFF + (size_t)N_ * 256 * 2)          // xl hi/lo grouped 102.4 MB
#define XRB_OFF  (XSP_OFF + (size_t)N_ * 512 * 2)          // xr bf16 51.2 MB
#define LG_OFF   (XRB_OFF + (size_t)N_ * 256 * 2)          // plog 6.4 MB
#define DG_OFF   (LG_OFF + (size_t)ETOT * 4 * 4)
#define OF_OFF   (DG_OFF + (size_t)N_ * 4)
#define CU_OFF   (OF_OFF + (size_t)(N_ + 32) * 4)
#define SR_OFF   (CU_OFF + (size_t)N_ * 4)
#define DP_OFF   (SR_OFF + (size_t)ETOT * 4)
#define PE_OFF   (DP_OFF + (size_t)ETOT * 4)
#define RN_OFF   (PE_OFF + (size_t)ETOT * 4)               // rnk [ETOT]
#define SC_OFF   (RN_OFF + (size_t)ETOT * 4)               // srcs_c [E_]
#define DC_OFF   (SC_OFF + (size_t)E_ * 4)                 // dstp_c [E_]
#define PC_OFF   (DC_OFF + (size_t)E_ * 4)                 // posr_c [E_]
#define BS_OFF   (PC_OFF + (size_t)E_ * 4)                 // bsum (scan1)
#define BS2_OFF  (BS_OFF + (size_t)512)                    // bsum2 (scan2) 391*4
#define MS_OFF   (BS2_OFF + (size_t)2048)
#define LE_OFF   (MS_OFF + (size_t)256)
#define WCH_OFF  (LE_OFF + (size_t)2048)
#define WCL_OFF  (WCH_OFF + (size_t)3 * 512 * 256 * 2)
#define WEH_OFF  (WCL_OFF + (size_t)3 * 512 * 256 * 2)
#define EAT_OFF  (WEH_OFF + (size_t)3 * 256 * 64 * 2)      // eattrb rank-ordered 38.4 MB

extern "C" void kernel_launch(void* const* d_in, const int* in_sizes, int n_in,
                              void* d_out, int out_size, void* d_ws, size_t ws_size,
                              hipStream_t stream) {
    const float* x     = (const float*)d_in[0];
    const int*   ei    = (const int*)d_in[1];
    const float* eattr = (const float*)d_in[2];
    const int*   batch = (const int*)d_in[3];
    const float* Wl    = (const float*)d_in[4];
    const float* bl    = (const float*)d_in[5];
    const float* Wr    = (const float*)d_in[6];
    const float* br    = (const float*)d_in[7];
    const float* We    = (const float*)d_in[8];
    const float* att   = (const float*)d_in[9];
    const float* bias  = (const float*)d_in[10];
    const float* Wp1   = (const float*)d_in[11];
    const float* bp1   = (const float*)d_in[12];
    const float* Wp2   = (const float*)d_in[13];
    const float* bp2   = (const float*)d_in[14];

    char* ws = (char*)d_ws;
    short*    xhi     = (short*)(ws + XHI_OFF);
    short*    xlo     = (short*)(ws + XLO_OFF);
    float*    w0      = (float*)(ws + W0_OFF);
    short*    xsp     = (short*)(ws + XSP_OFF);
    short*    xrb     = (short*)(ws + XRB_OFF);
    float*    plog    = (float*)(ws + LG_OFF);
    int*      deg     = (int*)(ws + DG_OFF);
    int*      off     = (int*)(ws + OF_OFF);
    int*      cursor  = (int*)(ws + CU_OFF);
    int*      srcs    = (int*)(ws + SR_OFF);
    int*      dstp    = (int*)(ws + DP_OFF);
    int*      pose    = (int*)(ws + PE_OFF);
    int*      rnk     = (int*)(ws + RN_OFF);
    int*      srcs_c  = (int*)(ws + SC_OFF);
    int*      dstp_c  = (int*)(ws + DC_OFF);
    int*      posr_c  = (int*)(ws + PC_OFF);
    int*      bsum    = (int*)(ws + BS_OFF);
    int*      bsum2   = (int*)(ws + BS2_OFF);
    float*    meansum = (float*)(ws + MS_OFF);
    float*    loope   = (float*)(ws + LE_OFF);
    short*    wcatH   = (short*)(ws + WCH_OFF);
    short*    wcatL   = (short*)(ws + WCL_OFF);
    short*    weH     = (short*)(ws + WEH_OFF);
    short*    eattrb  = (short*)(ws + EAT_OFF);

    // setup
    hipMemsetAsync(meansum, 0, 64 * 4, stream);
    hipMemsetAsync(deg, 0, (size_t)N_ * 4, stream);
    mean_kernel<<<512, 256, 0, stream>>>(eattr, meansum);
    prep_wcat_kernel<<<(3 * 512 * 256 + 255) / 256, 256, 0, stream>>>(Wl, Wr, wcatH, wcatL);
    prep_we_kernel<<<(3 * 256 * 64 + 255) / 256, 256, 0, stream>>>(We, weH);
    split_x_kernel<<<(N_ * 32 + 255) / 256, 256, 0, stream>>>(x, xhi, xlo);
    hist_kernel<<<(ETOT + 255) / 256, 256, 0, stream>>>(ei, deg);
    scanA_kernel<<<NB_SCAN, 256, 0, stream>>>(deg, off, bsum);
    scanB_kernel<<<1, 64, 0, stream>>>(bsum, NB_SCAN);
    scanC_kernel<<<(N_ + 255) / 256, 256, 0, stream>>>(off, bsum);
    hipMemcpyAsync(cursor, off, (size_t)N_ * 4, hipMemcpyDeviceToDevice, stream);
    scatter_kernel<<<(ETOT + 255) / 256, 256, 0, stream>>>(ei, cursor, srcs, dstp, pose);
    // rank-compaction of real edges (CSR order, gaps removed)
    scanA2_kernel<<<NB_SCAN2, 256, 0, stream>>>(srcs, dstp, rnk, bsum2);
    scanB_kernel<<<1, 64, 0, stream>>>(bsum2, NB_SCAN2);
    scanC2_kernel<<<(ETOT + 255) / 256, 256, 0, stream>>>(rnk, bsum2);
    compact_kernel<<<(ETOT + 255) / 256, 256, 0, stream>>>(srcs, dstp, rnk, srcs_c, dstp_c, posr_c);
    split_e_kernel<<<(E_ * 8 + 255) / 256, 256, 0, stream>>>(eattr, eattrb, pose, rnk);

    const int mtN = (N_ + BM - 1) / BM;         // 782
    const int nwgN = 4 * mtN;                   // 3128
    const int mtE = (E_ + 127) / 128;           // 2344
    const int nwgE = 2 * mtE;                   // 4688

    for (int l = 0; l < 3; l++) {
        const float* We_l = We + (size_t)l * 64 * 256;
        const float* att_l = att + (size_t)l * 256;
        loope_kernel<<<1, 256, 0, stream>>>(meansum, We_l, loope);
        // xl (hi/lo grouped) | xr (bf16), fp32-split 3-pass path
        mfma_gemm_node<<<nwgN, 256, 0, stream>>>(
            xhi, xlo, wcatH + (size_t)l * 512 * 256, wcatL + (size_t)l * 512 * 256,
            xsp, xrb, bl + (size_t)l * 256, br + (size_t)l * 256, N_, 256);
        edge_fused_kernel<<<nwgE, 256, 0, stream>>>(
            eattrb, weH + (size_t)l * 256 * 64, srcs_c, dstp_c, posr_c, xsp, xrb, att_l, plog);
        self_logits_kernel<<<(N_ + 3) / 4, 256, 0, stream>>>(xsp, xrb, loope, att_l, pose, plog);
        // fused softmax + aggregation
        // layers 0,1: write next layer's hi/lo splits (no fp32); layer 2: fp32 for pool
        agg_kernel<<<(N_ + 3) / 4, 256, 0, stream>>>(
            xsp, plog, off, srcs, bias + (size_t)l * 256,
            (l == 2) ? w0 : nullptr,
            (l < 2) ? xhi : nullptr,
            (l < 2) ? xlo : nullptr);
    }

    pool_mlp_kernel<<<G_, 256, 0, stream>>>(w0, batch, Wp1, bp1, Wp2, bp2, (float*)d_out);
}